// Round 1
// baseline (531.122 us; speedup 1.0000x reference)
//
#include <hip/hip_runtime.h>

#define NN 100000
#define NE 3200000
#define IN_F 128
#define OUT_F 64

// ---------------- degree kernel: count out/in degrees ----------------
__global__ void deg_kernel(const int* __restrict__ src, const int* __restrict__ dst,
                           int* __restrict__ deg_out, int* __restrict__ deg_in) {
    const int nq = NE / 4;  // 3.2M divisible by 4
    int i = blockIdx.x * blockDim.x + threadIdx.x;
    const int stride = gridDim.x * blockDim.x;
    const int4* src4 = (const int4*)src;
    const int4* dst4 = (const int4*)dst;
    for (; i < nq; i += stride) {
        int4 s = src4[i];
        int4 d = dst4[i];
        atomicAdd(&deg_out[s.x], 1);
        atomicAdd(&deg_out[s.y], 1);
        atomicAdd(&deg_out[s.z], 1);
        atomicAdd(&deg_out[s.w], 1);
        atomicAdd(&deg_in[d.x], 1);
        atomicAdd(&deg_in[d.y], 1);
        atomicAdd(&deg_in[d.z], 1);
        atomicAdd(&deg_in[d.w], 1);
    }
}

// ---------------- w̄ = row-means of W, b̄ = mean of b ----------------
__global__ void wbar_kernel(const float* __restrict__ W, const float* __restrict__ b,
                            float* __restrict__ wbar, float* __restrict__ bbar) {
    int k = threadIdx.x;  // 128 threads
    float s = 0.f;
    for (int j = 0; j < OUT_F; ++j) s += W[k * OUT_F + j];
    wbar[k] = s * (1.0f / OUT_F);
    if (k == 0) {
        float sb = 0.f;
        for (int j = 0; j < OUT_F; ++j) sb += b[j];
        *bbar = sb * (1.0f / OUT_F);
    }
}

// ---------------- s[i] = rsqrt(max(deg_out,1)) * dot(features[i], wbar) ----------------
// one wave (64 lanes) per node; lane l handles feats [2l, 2l+1]
__global__ void node_scalar_kernel(const float* __restrict__ features,
                                   const int* __restrict__ deg_out,
                                   const float* __restrict__ wbar,
                                   float* __restrict__ sval) {
    const int lane = threadIdx.x & 63;
    const int wave = threadIdx.x >> 6;
    const int node = blockIdx.x * 4 + wave;  // 4 waves / block of 256
    if (node >= NN) return;
    const float2* f2 = (const float2*)(features + (size_t)node * IN_F);
    const float2* w2 = (const float2*)wbar;
    float2 f = f2[lane];
    float2 w = w2[lane];
    float p = f.x * w.x + f.y * w.y;
    #pragma unroll
    for (int off = 32; off > 0; off >>= 1) p += __shfl_down(p, off);
    if (lane == 0) {
        float d = (float)deg_out[node];
        sval[node] = p * rsqrtf(fmaxf(d, 1.0f));
    }
}

// ---------------- scatter: agg[dst] += s[src] ----------------
__global__ void scatter_kernel(const int* __restrict__ src, const int* __restrict__ dst,
                               const float* __restrict__ sval, float* __restrict__ agg) {
    const int nq = NE / 4;
    int i = blockIdx.x * blockDim.x + threadIdx.x;
    const int stride = gridDim.x * blockDim.x;
    const int4* src4 = (const int4*)src;
    const int4* dst4 = (const int4*)dst;
    for (; i < nq; i += stride) {
        int4 s = src4[i];
        int4 d = dst4[i];
        float v0 = sval[s.x];
        float v1 = sval[s.y];
        float v2 = sval[s.z];
        float v3 = sval[s.w];
        atomicAdd(&agg[d.x], v0);
        atomicAdd(&agg[d.y], v1);
        atomicAdd(&agg[d.z], v2);
        atomicAdd(&agg[d.w], v3);
    }
}

// ---------------- finalize: out[n] = agg[n]*rsqrt(max(deg_in,1)) + bbar ----------------
__global__ void final_kernel(const float* __restrict__ agg, const int* __restrict__ deg_in,
                             const float* __restrict__ bbar, float* __restrict__ out) {
    int n = blockIdx.x * blockDim.x + threadIdx.x;
    if (n >= NN) return;
    float d = (float)deg_in[n];
    out[n] = agg[n] * rsqrtf(fmaxf(d, 1.0f)) + *bbar;
}

extern "C" void kernel_launch(void* const* d_in, const int* in_sizes, int n_in,
                              void* d_out, int out_size, void* d_ws, size_t ws_size,
                              hipStream_t stream) {
    const float* features = (const float*)d_in[0];
    const float* W        = (const float*)d_in[1];
    const float* b        = (const float*)d_in[2];
    const int*   src      = (const int*)d_in[3];
    const int*   dst      = (const int*)d_in[4];
    float* out = (float*)d_out;

    // workspace layout (all 4-byte elements):
    // [0, NN)        deg_out (int)
    // [NN, 2NN)      deg_in  (int)
    // [2NN, 3NN)     agg     (float)  -- must be zeroed
    // [3NN, 4NN)     sval    (float)
    // [4NN, 4NN+128) wbar    (float)
    // [4NN+128]      bbar    (float)
    int*   deg_out = (int*)d_ws;
    int*   deg_in  = deg_out + NN;
    float* agg     = (float*)(deg_in + NN);
    float* sval    = agg + NN;
    float* wbar    = sval + NN;
    float* bbar    = wbar + IN_F;

    // zero deg_out, deg_in, agg (contiguous 3*NN words); ws is poisoned each call
    hipMemsetAsync(d_ws, 0, (size_t)3 * NN * sizeof(int), stream);

    wbar_kernel<<<1, 128, 0, stream>>>(W, b, wbar, bbar);
    deg_kernel<<<2048, 256, 0, stream>>>(src, dst, deg_out, deg_in);
    node_scalar_kernel<<<(NN + 3) / 4, 256, 0, stream>>>(features, deg_out, wbar, sval);
    scatter_kernel<<<2048, 256, 0, stream>>>(src, dst, sval, agg);
    final_kernel<<<(NN + 255) / 256, 256, 0, stream>>>(agg, deg_in, bbar, out);
}

// Round 3
// 285.711 us; speedup vs baseline: 1.8589x; 1.8589x over previous
//
#include <hip/hip_runtime.h>

#define NN 100000
#define NE 3200000
#define IN_F 128
#define OUT_F 64

// bucketing: node buckets of width 128
#define BW_SHIFT 7
#define BWIDTH 128
#define NB 782              // ceil(100000/128)
#define CB 256              // count/scatter blocks
#define EPB (NE / CB)       // 12500 edges per block (divisible by 4)

// ---------------- w-bar / b-bar ----------------
__global__ void wbar_kernel(const float* __restrict__ W, const float* __restrict__ b,
                            float* __restrict__ wbar, float* __restrict__ bbar) {
    int k = threadIdx.x;  // 128 threads
    float s = 0.f;
    for (int j = 0; j < OUT_F; ++j) s += W[k * OUT_F + j];
    wbar[k] = s * (1.0f / OUT_F);
    if (k == 0) {
        float sb = 0.f;
        for (int j = 0; j < OUT_F; ++j) sb += b[j];
        *bbar = sb * (1.0f / OUT_F);
    }
}

// ---------------- phase 1: per-(block,bucket) counts ----------------
__global__ __launch_bounds__(256) void count_kernel(const int* __restrict__ src,
                                                    const int* __restrict__ dst,
                                                    int* __restrict__ cntS,
                                                    int* __restrict__ cntD) {
    __shared__ int hs[NB];
    __shared__ int hd[NB];
    const int b = blockIdx.x;
    for (int k = threadIdx.x; k < NB; k += 256) { hs[k] = 0; hd[k] = 0; }
    __syncthreads();
    const int4* s4 = (const int4*)(src + b * EPB);
    const int4* d4 = (const int4*)(dst + b * EPB);
    const int nq = EPB / 4;
    for (int i = threadIdx.x; i < nq; i += 256) {
        int4 s = s4[i];
        int4 d = d4[i];
        atomicAdd(&hs[s.x >> BW_SHIFT], 1);
        atomicAdd(&hs[s.y >> BW_SHIFT], 1);
        atomicAdd(&hs[s.z >> BW_SHIFT], 1);
        atomicAdd(&hs[s.w >> BW_SHIFT], 1);
        atomicAdd(&hd[d.x >> BW_SHIFT], 1);
        atomicAdd(&hd[d.y >> BW_SHIFT], 1);
        atomicAdd(&hd[d.z >> BW_SHIFT], 1);
        atomicAdd(&hd[d.w >> BW_SHIFT], 1);
    }
    __syncthreads();
    for (int k = threadIdx.x; k < NB; k += 256) {
        cntS[b * NB + k] = hs[k];
        cntD[b * NB + k] = hd[k];
    }
}

// ---------------- phase 2: exact positions (in-place cnt -> pos) ----------------
__global__ __launch_bounds__(800) void prefix_kernel(int* __restrict__ cnt, int* __restrict__ bbase) {
    __shared__ int colsum[NB];
    __shared__ int basesh[NB];
    const int k = threadIdx.x;
    if (k < NB) {
        int s = 0;
        for (int b = 0; b < CB; ++b) s += cnt[b * NB + k];
        colsum[k] = s;
    }
    __syncthreads();
    if (k == 0) {
        int run = 0;
        for (int i = 0; i < NB; ++i) { basesh[i] = run; run += colsum[i]; }
        bbase[NB] = run;  // == NE
    }
    __syncthreads();
    if (k < NB) {
        bbase[k] = basesh[k];
        int run = basesh[k];
        for (int b = 0; b < CB; ++b) {
            int c = cnt[b * NB + k];
            cnt[b * NB + k] = run;
            run += c;
        }
    }
}

// ---------------- phase 3: scatter into buckets ----------------
__global__ __launch_bounds__(256) void scatter_bin_kernel(const int* __restrict__ src,
                                                          const int* __restrict__ dst,
                                                          const int* __restrict__ posS,
                                                          const int* __restrict__ posD,
                                                          int* __restrict__ binned_src,
                                                          int2* __restrict__ binned_pair) {
    __shared__ int curS[NB];
    __shared__ int curD[NB];
    const int b = blockIdx.x;
    for (int k = threadIdx.x; k < NB; k += 256) {
        curS[k] = posS[b * NB + k];
        curD[k] = posD[b * NB + k];
    }
    __syncthreads();
    const int4* s4 = (const int4*)(src + b * EPB);
    const int4* d4 = (const int4*)(dst + b * EPB);
    const int nq = EPB / 4;
    for (int i = threadIdx.x; i < nq; i += 256) {
        int4 s = s4[i];
        int4 d = d4[i];
        int p;
        p = atomicAdd(&curS[s.x >> BW_SHIFT], 1); binned_src[p] = s.x;
        p = atomicAdd(&curS[s.y >> BW_SHIFT], 1); binned_src[p] = s.y;
        p = atomicAdd(&curS[s.z >> BW_SHIFT], 1); binned_src[p] = s.z;
        p = atomicAdd(&curS[s.w >> BW_SHIFT], 1); binned_src[p] = s.w;
        p = atomicAdd(&curD[d.x >> BW_SHIFT], 1); binned_pair[p] = make_int2(s.x, d.x);
        p = atomicAdd(&curD[d.y >> BW_SHIFT], 1); binned_pair[p] = make_int2(s.y, d.y);
        p = atomicAdd(&curD[d.z >> BW_SHIFT], 1); binned_pair[p] = make_int2(s.z, d.z);
        p = atomicAdd(&curD[d.w >> BW_SHIFT], 1); binned_pair[p] = make_int2(s.w, d.w);
    }
}

// ---------------- phase 4: out-degree norm per bucket ----------------
__global__ __launch_bounds__(256) void degnorm_kernel(const int* __restrict__ binned_src,
                                                      const int* __restrict__ bbaseS,
                                                      float* __restrict__ out_norm) {
    __shared__ int cnt[BWIDTH];
    const int k = blockIdx.x;
    const int t = threadIdx.x;
    if (t < BWIDTH) cnt[t] = 0;
    __syncthreads();
    const int lo = bbaseS[k], hi = bbaseS[k + 1];
    for (int i = lo + t; i < hi; i += 256) atomicAdd(&cnt[binned_src[i] & (BWIDTH - 1)], 1);
    __syncthreads();
    if (t < BWIDTH) {
        int node = (k << BW_SHIFT) + t;
        if (node < NN) out_norm[node] = rsqrtf(fmaxf((float)cnt[t], 1.0f));
    }
}

// ---------------- s[i] = out_norm[i] * dot(features[i], wbar) ----------------
__global__ __launch_bounds__(256) void node_scalar_kernel(const float* __restrict__ features,
                                                          const float* __restrict__ out_norm,
                                                          const float* __restrict__ wbar,
                                                          float* __restrict__ sval) {
    const int lane = threadIdx.x & 63;
    const int wave = threadIdx.x >> 6;
    const int node = blockIdx.x * 4 + wave;
    if (node >= NN) return;
    const float2* f2 = (const float2*)(features + (size_t)node * IN_F);
    const float2* w2 = (const float2*)wbar;
    float2 f = f2[lane];
    float2 w = w2[lane];
    float p = f.x * w.x + f.y * w.y;
    #pragma unroll
    for (int off = 32; off > 0; off >>= 1) p += __shfl_down(p, off);
    if (lane == 0) sval[node] = p * out_norm[node];
}

// ---------------- phase 5: per-bucket accumulate + finalize ----------------
__global__ __launch_bounds__(256) void accum_kernel(const int2* __restrict__ binned_pair,
                                                    const int* __restrict__ bbaseD,
                                                    const float* __restrict__ sval,
                                                    const float* __restrict__ bbar,
                                                    float* __restrict__ out) {
    __shared__ float agg[BWIDTH];
    __shared__ int cnt[BWIDTH];
    const int k = blockIdx.x;
    const int t = threadIdx.x;
    if (t < BWIDTH) { agg[t] = 0.f; cnt[t] = 0; }
    __syncthreads();
    const int lo = bbaseD[k], hi = bbaseD[k + 1];
    for (int i = lo + t; i < hi; i += 256) {
        int2 p = binned_pair[i];
        float v = sval[p.x];
        int loc = p.y & (BWIDTH - 1);
        atomicAdd(&agg[loc], v);
        atomicAdd(&cnt[loc], 1);
    }
    __syncthreads();
    if (t < BWIDTH) {
        int node = (k << BW_SHIFT) + t;
        if (node < NN) out[node] = agg[t] * rsqrtf(fmaxf((float)cnt[t], 1.0f)) + bbar[0];
    }
}

// ================= fallback (R1 atomic path, needs only ~1.6 MB ws) =================
__global__ void deg_kernel(const int* __restrict__ src, const int* __restrict__ dst,
                           int* __restrict__ deg_out, int* __restrict__ deg_in) {
    const int nq = NE / 4;
    int i = blockIdx.x * blockDim.x + threadIdx.x;
    const int stride = gridDim.x * blockDim.x;
    const int4* src4 = (const int4*)src;
    const int4* dst4 = (const int4*)dst;
    for (; i < nq; i += stride) {
        int4 s = src4[i];
        int4 d = dst4[i];
        atomicAdd(&deg_out[s.x], 1); atomicAdd(&deg_out[s.y], 1);
        atomicAdd(&deg_out[s.z], 1); atomicAdd(&deg_out[s.w], 1);
        atomicAdd(&deg_in[d.x], 1);  atomicAdd(&deg_in[d.y], 1);
        atomicAdd(&deg_in[d.z], 1);  atomicAdd(&deg_in[d.w], 1);
    }
}
__global__ void node_scalar_deg_kernel(const float* __restrict__ features,
                                       const int* __restrict__ deg_out,
                                       const float* __restrict__ wbar,
                                       float* __restrict__ sval) {
    const int lane = threadIdx.x & 63;
    const int wave = threadIdx.x >> 6;
    const int node = blockIdx.x * 4 + wave;
    if (node >= NN) return;
    const float2* f2 = (const float2*)(features + (size_t)node * IN_F);
    const float2* w2 = (const float2*)wbar;
    float2 f = f2[lane];
    float2 w = w2[lane];
    float p = f.x * w.x + f.y * w.y;
    #pragma unroll
    for (int off = 32; off > 0; off >>= 1) p += __shfl_down(p, off);
    if (lane == 0) {
        float d = (float)deg_out[node];
        sval[node] = p * rsqrtf(fmaxf(d, 1.0f));
    }
}
__global__ void scatter_kernel(const int* __restrict__ src, const int* __restrict__ dst,
                               const float* __restrict__ sval, float* __restrict__ agg) {
    const int nq = NE / 4;
    int i = blockIdx.x * blockDim.x + threadIdx.x;
    const int stride = gridDim.x * blockDim.x;
    const int4* src4 = (const int4*)src;
    const int4* dst4 = (const int4*)dst;
    for (; i < nq; i += stride) {
        int4 s = src4[i];
        int4 d = dst4[i];
        atomicAdd(&agg[d.x], sval[s.x]);
        atomicAdd(&agg[d.y], sval[s.y]);
        atomicAdd(&agg[d.z], sval[s.z]);
        atomicAdd(&agg[d.w], sval[s.w]);
    }
}
__global__ void final_kernel(const float* __restrict__ agg, const int* __restrict__ deg_in,
                             const float* __restrict__ bbar, float* __restrict__ out) {
    int n = blockIdx.x * blockDim.x + threadIdx.x;
    if (n >= NN) return;
    float d = (float)deg_in[n];
    out[n] = agg[n] * rsqrtf(fmaxf(d, 1.0f)) + *bbar;
}

extern "C" void kernel_launch(void* const* d_in, const int* in_sizes, int n_in,
                              void* d_out, int out_size, void* d_ws, size_t ws_size,
                              hipStream_t stream) {
    const float* features = (const float*)d_in[0];
    const float* W        = (const float*)d_in[1];
    const float* b        = (const float*)d_in[2];
    const int*   src      = (const int*)d_in[3];
    const int*   dst      = (const int*)d_in[4];
    float* out = (float*)d_out;

    // fast-path workspace layout (4-byte words, binned_pair first for 8B alignment):
    // [0, 2*NE)                  binned_pair (int2)
    // [2NE, 3NE)                 binned_src
    // [3NE, 3NE+CB*NB)           cntS/posS
    // [+CB*NB]                   cntD/posD
    // [+NB+1]                    bbaseS
    // [+NB+1]                    bbaseD
    // [+NN]                      out_norm
    // [+NN]                      sval
    // [+128]                     wbar
    // [+1]                       bbar
    size_t need_words = (size_t)3 * NE + 2 * (size_t)CB * NB + 2 * (NB + 1) + 2 * NN + IN_F + 1;
    if (ws_size >= need_words * 4 + 64) {
        int* w_ = (int*)d_ws;
        int2* binned_pair = (int2*)w_;
        int*  binned_src  = w_ + (size_t)2 * NE;
        int*  cntS        = binned_src + NE;
        int*  cntD        = cntS + (size_t)CB * NB;
        int*  bbaseS      = cntD + (size_t)CB * NB;
        int*  bbaseD      = bbaseS + (NB + 1);
        float* out_norm   = (float*)(bbaseD + (NB + 1));
        float* sval       = out_norm + NN;
        float* wbar       = sval + NN;
        float* bbar       = wbar + IN_F;

        wbar_kernel<<<1, 128, 0, stream>>>(W, b, wbar, bbar);
        count_kernel<<<CB, 256, 0, stream>>>(src, dst, cntS, cntD);
        prefix_kernel<<<1, 800, 0, stream>>>(cntS, bbaseS);
        prefix_kernel<<<1, 800, 0, stream>>>(cntD, bbaseD);
        scatter_bin_kernel<<<CB, 256, 0, stream>>>(src, dst, cntS, cntD, binned_src, binned_pair);
        degnorm_kernel<<<NB, 256, 0, stream>>>(binned_src, bbaseS, out_norm);
        node_scalar_kernel<<<(NN + 3) / 4, 256, 0, stream>>>(features, out_norm, wbar, sval);
        accum_kernel<<<NB, 256, 0, stream>>>(binned_pair, bbaseD, sval, bbar, out);
    } else {
        // fallback: R1 atomic path
        int*   deg_out = (int*)d_ws;
        int*   deg_in  = deg_out + NN;
        float* agg     = (float*)(deg_in + NN);
        float* sval    = agg + NN;
        float* wbar    = sval + NN;
        float* bbar    = wbar + IN_F;
        hipMemsetAsync(d_ws, 0, (size_t)3 * NN * sizeof(int), stream);
        wbar_kernel<<<1, 128, 0, stream>>>(W, b, wbar, bbar);
        deg_kernel<<<2048, 256, 0, stream>>>(src, dst, deg_out, deg_in);
        node_scalar_deg_kernel<<<(NN + 3) / 4, 256, 0, stream>>>(features, deg_out, wbar, sval);
        scatter_kernel<<<2048, 256, 0, stream>>>(src, dst, sval, agg);
        final_kernel<<<(NN + 255) / 256, 256, 0, stream>>>(agg, deg_in, bbar, out);
    }
}

// Round 5
// 212.755 us; speedup vs baseline: 2.4964x; 1.3429x over previous
//
#include <hip/hip_runtime.h>

#define NN 100000
#define NE 3200000
#define IN_F 128
#define OUT_F 64

// bucketing: node buckets of width 512
#define BW_SHIFT 9
#define BWIDTH 512
#define NB 196              // ceil(100000/512)
#define CB 256              // count/scatter blocks
#define EPB (NE / CB)       // 12500 edges per block (divisible by 4)

// ---------------- w-bar / b-bar ----------------
__global__ void wbar_kernel(const float* __restrict__ W, const float* __restrict__ b,
                            float* __restrict__ wbar, float* __restrict__ bbar) {
    int k = threadIdx.x;  // 128 threads
    float s = 0.f;
    for (int j = 0; j < OUT_F; ++j) s += W[k * OUT_F + j];
    wbar[k] = s * (1.0f / OUT_F);
    if (k == 0) {
        float sb = 0.f;
        for (int j = 0; j < OUT_F; ++j) sb += b[j];
        *bbar = sb * (1.0f / OUT_F);
    }
}

// ---------------- phase 1: per-(block,bucket) counts, bucket-major output ----------------
__global__ __launch_bounds__(256) void count_kernel(const int* __restrict__ src,
                                                    const int* __restrict__ dst,
                                                    int* __restrict__ cntS,
                                                    int* __restrict__ cntD) {
    __shared__ int hs[NB];
    __shared__ int hd[NB];
    const int b = blockIdx.x;
    for (int k = threadIdx.x; k < NB; k += 256) { hs[k] = 0; hd[k] = 0; }
    __syncthreads();
    const int4* s4 = (const int4*)(src + b * EPB);
    const int4* d4 = (const int4*)(dst + b * EPB);
    const int nq = EPB / 4;
    for (int i = threadIdx.x; i < nq; i += 256) {
        int4 s = s4[i];
        int4 d = d4[i];
        atomicAdd(&hs[s.x >> BW_SHIFT], 1);
        atomicAdd(&hs[s.y >> BW_SHIFT], 1);
        atomicAdd(&hs[s.z >> BW_SHIFT], 1);
        atomicAdd(&hs[s.w >> BW_SHIFT], 1);
        atomicAdd(&hd[d.x >> BW_SHIFT], 1);
        atomicAdd(&hd[d.y >> BW_SHIFT], 1);
        atomicAdd(&hd[d.z >> BW_SHIFT], 1);
        atomicAdd(&hd[d.w >> BW_SHIFT], 1);
    }
    __syncthreads();
    // bucket-major: column k is contiguous over blocks b
    for (int k = threadIdx.x; k < NB; k += 256) {
        cntS[k * CB + b] = hs[k];
        cntD[k * CB + b] = hd[k];
    }
}

// ---------------- phase 2a: per-bucket exclusive scan over the 256 block-counts ----------------
// grid = 2*NB blocks; block c < NB handles cntS column c, else cntD column c-NB.
__global__ __launch_bounds__(256) void colscan_kernel(int* __restrict__ cntS,
                                                      int* __restrict__ cntD,
                                                      int* __restrict__ colsum) {
    __shared__ int sh[CB];
    const int c = blockIdx.x;
    int* col = (c < NB) ? (cntS + (size_t)c * CB) : (cntD + (size_t)(c - NB) * CB);
    const int t = threadIdx.x;
    int v = col[t];
    sh[t] = v;
    __syncthreads();
    // Hillis-Steele inclusive scan
    #pragma unroll
    for (int off = 1; off < CB; off <<= 1) {
        int x = (t >= off) ? sh[t - off] : 0;
        __syncthreads();
        sh[t] += x;
        __syncthreads();
    }
    col[t] = sh[t] - v;            // exclusive within-bucket position
    if (t == CB - 1) colsum[c] = sh[t];
}

// ---------------- phase 2b: bucket base offsets (196 values each, tiny) ----------------
__global__ __launch_bounds__(256) void basescan_kernel(const int* __restrict__ colsum,
                                                       int* __restrict__ bbaseS,
                                                       int* __restrict__ bbaseD) {
    __shared__ int sh[2 * NB];
    for (int i = threadIdx.x; i < 2 * NB; i += 256) sh[i] = colsum[i];
    __syncthreads();
    if (threadIdx.x == 0) {
        int run = 0;
        for (int k = 0; k < NB; ++k) { bbaseS[k] = run; run += sh[k]; }
        bbaseS[NB] = run;
    }
    if (threadIdx.x == 64) {
        int run = 0;
        for (int k = 0; k < NB; ++k) { bbaseD[k] = run; run += sh[NB + k]; }
        bbaseD[NB] = run;
    }
}

// ---------------- phase 3: scatter into buckets (packed payloads) ----------------
__global__ __launch_bounds__(256) void scatter_bin_kernel(const int* __restrict__ src,
                                                          const int* __restrict__ dst,
                                                          const int* __restrict__ posS,
                                                          const int* __restrict__ posD,
                                                          const int* __restrict__ bbaseS,
                                                          const int* __restrict__ bbaseD,
                                                          unsigned short* __restrict__ binned_srcloc,
                                                          int* __restrict__ binned_pack) {
    __shared__ int curS[NB];
    __shared__ int curD[NB];
    const int b = blockIdx.x;
    for (int k = threadIdx.x; k < NB; k += 256) {
        curS[k] = posS[k * CB + b] + bbaseS[k];
        curD[k] = posD[k * CB + b] + bbaseD[k];
    }
    __syncthreads();
    const int4* s4 = (const int4*)(src + b * EPB);
    const int4* d4 = (const int4*)(dst + b * EPB);
    const int nq = EPB / 4;
    for (int i = threadIdx.x; i < nq; i += 256) {
        int4 s = s4[i];
        int4 d = d4[i];
        int p;
        p = atomicAdd(&curS[s.x >> BW_SHIFT], 1); binned_srcloc[p] = (unsigned short)(s.x & (BWIDTH - 1));
        p = atomicAdd(&curS[s.y >> BW_SHIFT], 1); binned_srcloc[p] = (unsigned short)(s.y & (BWIDTH - 1));
        p = atomicAdd(&curS[s.z >> BW_SHIFT], 1); binned_srcloc[p] = (unsigned short)(s.z & (BWIDTH - 1));
        p = atomicAdd(&curS[s.w >> BW_SHIFT], 1); binned_srcloc[p] = (unsigned short)(s.w & (BWIDTH - 1));
        // pack: src node id (17 bits) | dst local id (9 bits) << 17
        p = atomicAdd(&curD[d.x >> BW_SHIFT], 1); binned_pack[p] = s.x | ((d.x & (BWIDTH - 1)) << 17);
        p = atomicAdd(&curD[d.y >> BW_SHIFT], 1); binned_pack[p] = s.y | ((d.y & (BWIDTH - 1)) << 17);
        p = atomicAdd(&curD[d.z >> BW_SHIFT], 1); binned_pack[p] = s.z | ((d.z & (BWIDTH - 1)) << 17);
        p = atomicAdd(&curD[d.w >> BW_SHIFT], 1); binned_pack[p] = s.w | ((d.w & (BWIDTH - 1)) << 17);
    }
}

// ---------------- phase 4: out-degree norm per bucket ----------------
__global__ __launch_bounds__(256) void degnorm_kernel(const unsigned short* __restrict__ binned_srcloc,
                                                      const int* __restrict__ bbaseS,
                                                      float* __restrict__ out_norm) {
    __shared__ int cnt[BWIDTH];
    const int k = blockIdx.x;
    const int t = threadIdx.x;
    for (int i = t; i < BWIDTH; i += 256) cnt[i] = 0;
    __syncthreads();
    const int lo = bbaseS[k], hi = bbaseS[k + 1];
    for (int i = lo + t; i < hi; i += 256) atomicAdd(&cnt[binned_srcloc[i]], 1);
    __syncthreads();
    for (int i = t; i < BWIDTH; i += 256) {
        int node = (k << BW_SHIFT) + i;
        if (node < NN) out_norm[node] = rsqrtf(fmaxf((float)cnt[i], 1.0f));
    }
}

// ---------------- s[i] = out_norm[i] * dot(features[i], wbar) ----------------
__global__ __launch_bounds__(256) void node_scalar_kernel(const float* __restrict__ features,
                                                          const float* __restrict__ out_norm,
                                                          const float* __restrict__ wbar,
                                                          float* __restrict__ sval) {
    const int lane = threadIdx.x & 63;
    const int wave = threadIdx.x >> 6;
    const int node = blockIdx.x * 4 + wave;
    if (node >= NN) return;
    const float2* f2 = (const float2*)(features + (size_t)node * IN_F);
    const float2* w2 = (const float2*)wbar;
    float2 f = f2[lane];
    float2 w = w2[lane];
    float p = f.x * w.x + f.y * w.y;
    #pragma unroll
    for (int off = 32; off > 0; off >>= 1) p += __shfl_down(p, off);
    if (lane == 0) sval[node] = p * out_norm[node];
}

// ---------------- phase 5: per-bucket accumulate + finalize ----------------
__global__ __launch_bounds__(256) void accum_kernel(const int* __restrict__ binned_pack,
                                                    const int* __restrict__ bbaseD,
                                                    const float* __restrict__ sval,
                                                    const float* __restrict__ bbar,
                                                    float* __restrict__ out) {
    __shared__ float agg[BWIDTH];
    __shared__ int cnt[BWIDTH];
    const int k = blockIdx.x;
    const int t = threadIdx.x;
    for (int i = t; i < BWIDTH; i += 256) { agg[i] = 0.f; cnt[i] = 0; }
    __syncthreads();
    const int lo = bbaseD[k], hi = bbaseD[k + 1];
    for (int i = lo + t; i < hi; i += 256) {
        int p = binned_pack[i];
        int s = p & 0x1FFFF;
        int loc = (p >> 17) & (BWIDTH - 1);
        float v = sval[s];
        atomicAdd(&agg[loc], v);
        atomicAdd(&cnt[loc], 1);
    }
    __syncthreads();
    for (int i = t; i < BWIDTH; i += 256) {
        int node = (k << BW_SHIFT) + i;
        if (node < NN) out[node] = agg[i] * rsqrtf(fmaxf((float)cnt[i], 1.0f)) + bbar[0];
    }
}

// ================= fallback (R1 atomic path, needs only ~1.6 MB ws) =================
__global__ void deg_kernel(const int* __restrict__ src, const int* __restrict__ dst,
                           int* __restrict__ deg_out, int* __restrict__ deg_in) {
    const int nq = NE / 4;
    int i = blockIdx.x * blockDim.x + threadIdx.x;
    const int stride = gridDim.x * blockDim.x;
    const int4* src4 = (const int4*)src;
    const int4* dst4 = (const int4*)dst;
    for (; i < nq; i += stride) {
        int4 s = src4[i];
        int4 d = dst4[i];
        atomicAdd(&deg_out[s.x], 1); atomicAdd(&deg_out[s.y], 1);
        atomicAdd(&deg_out[s.z], 1); atomicAdd(&deg_out[s.w], 1);
        atomicAdd(&deg_in[d.x], 1);  atomicAdd(&deg_in[d.y], 1);
        atomicAdd(&deg_in[d.z], 1);  atomicAdd(&deg_in[d.w], 1);
    }
}
__global__ void node_scalar_deg_kernel(const float* __restrict__ features,
                                       const int* __restrict__ deg_out,
                                       const float* __restrict__ wbar,
                                       float* __restrict__ sval) {
    const int lane = threadIdx.x & 63;
    const int wave = threadIdx.x >> 6;
    const int node = blockIdx.x * 4 + wave;
    if (node >= NN) return;
    const float2* f2 = (const float2*)(features + (size_t)node * IN_F);
    const float2* w2 = (const float2*)wbar;
    float2 f = f2[lane];
    float2 w = w2[lane];
    float p = f.x * w.x + f.y * w.y;
    #pragma unroll
    for (int off = 32; off > 0; off >>= 1) p += __shfl_down(p, off);
    if (lane == 0) {
        float d = (float)deg_out[node];
        sval[node] = p * rsqrtf(fmaxf(d, 1.0f));
    }
}
__global__ void scatter_kernel(const int* __restrict__ src, const int* __restrict__ dst,
                               const float* __restrict__ sval, float* __restrict__ agg) {
    const int nq = NE / 4;
    int i = blockIdx.x * blockDim.x + threadIdx.x;
    const int stride = gridDim.x * blockDim.x;
    const int4* src4 = (const int4*)src;
    const int4* dst4 = (const int4*)dst;
    for (; i < nq; i += stride) {
        int4 s = src4[i];
        int4 d = dst4[i];
        atomicAdd(&agg[d.x], sval[s.x]);
        atomicAdd(&agg[d.y], sval[s.y]);
        atomicAdd(&agg[d.z], sval[s.z]);
        atomicAdd(&agg[d.w], sval[s.w]);
    }
}
__global__ void final_kernel(const float* __restrict__ agg, const int* __restrict__ deg_in,
                             const float* __restrict__ bbar, float* __restrict__ out) {
    int n = blockIdx.x * blockDim.x + threadIdx.x;
    if (n >= NN) return;
    float d = (float)deg_in[n];
    out[n] = agg[n] * rsqrtf(fmaxf(d, 1.0f)) + *bbar;
}

extern "C" void kernel_launch(void* const* d_in, const int* in_sizes, int n_in,
                              void* d_out, int out_size, void* d_ws, size_t ws_size,
                              hipStream_t stream) {
    const float* features = (const float*)d_in[0];
    const float* W        = (const float*)d_in[1];
    const float* b        = (const float*)d_in[2];
    const int*   src      = (const int*)d_in[3];
    const int*   dst      = (const int*)d_in[4];
    float* out = (float*)d_out;

    // fast-path workspace layout (4-byte words):
    // [0, NE)              binned_pack (int)
    // [NE, NE+NE/2)        binned_srcloc (ushort[NE])
    // [+NB*CB]             cntS/posS
    // [+NB*CB]             cntD/posD
    // [+2*NB]              colsum
    // [+NB+1]              bbaseS
    // [+NB+1]              bbaseD
    // [+NN]                out_norm
    // [+NN]                sval
    // [+128]               wbar
    // [+1]                 bbar
    size_t need_words = (size_t)NE + NE / 2 + 2 * (size_t)NB * CB + 2 * NB + 2 * (NB + 1)
                      + 2 * (size_t)NN + IN_F + 1;
    if (ws_size >= need_words * 4 + 64) {
        int* w_ = (int*)d_ws;
        int*  binned_pack          = w_;
        unsigned short* binned_srcloc = (unsigned short*)(w_ + NE);
        int*  cntS        = w_ + NE + NE / 2;
        int*  cntD        = cntS + (size_t)NB * CB;
        int*  colsum      = cntD + (size_t)NB * CB;
        int*  bbaseS      = colsum + 2 * NB;
        int*  bbaseD      = bbaseS + (NB + 1);
        float* out_norm   = (float*)(bbaseD + (NB + 1));
        float* sval       = out_norm + NN;
        float* wbar       = sval + NN;
        float* bbar       = wbar + IN_F;

        wbar_kernel<<<1, 128, 0, stream>>>(W, b, wbar, bbar);
        count_kernel<<<CB, 256, 0, stream>>>(src, dst, cntS, cntD);
        colscan_kernel<<<2 * NB, 256, 0, stream>>>(cntS, cntD, colsum);
        basescan_kernel<<<1, 256, 0, stream>>>(colsum, bbaseS, bbaseD);
        scatter_bin_kernel<<<CB, 256, 0, stream>>>(src, dst, cntS, cntD, bbaseS, bbaseD,
                                                   binned_srcloc, binned_pack);
        degnorm_kernel<<<NB, 256, 0, stream>>>(binned_srcloc, bbaseS, out_norm);
        node_scalar_kernel<<<(NN + 3) / 4, 256, 0, stream>>>(features, out_norm, wbar, sval);
        accum_kernel<<<NB, 256, 0, stream>>>(binned_pack, bbaseD, sval, bbar, out);
    } else {
        // fallback: R1 atomic path
        int*   deg_out = (int*)d_ws;
        int*   deg_in  = deg_out + NN;
        float* agg     = (float*)(deg_in + NN);
        float* sval    = agg + NN;
        float* wbar    = sval + NN;
        float* bbar    = wbar + IN_F;
        hipMemsetAsync(d_ws, 0, (size_t)3 * NN * sizeof(int), stream);
        wbar_kernel<<<1, 128, 0, stream>>>(W, b, wbar, bbar);
        deg_kernel<<<2048, 256, 0, stream>>>(src, dst, deg_out, deg_in);
        node_scalar_deg_kernel<<<(NN + 3) / 4, 256, 0, stream>>>(features, deg_out, wbar, sval);
        scatter_kernel<<<2048, 256, 0, stream>>>(src, dst, sval, agg);
        final_kernel<<<(NN + 255) / 256, 256, 0, stream>>>(agg, deg_in, bbar, out);
    }
}

// Round 6
// 193.277 us; speedup vs baseline: 2.7480x; 1.1008x over previous
//
#include <hip/hip_runtime.h>

#define NN 100000
#define NE 3200000
#define IN_F 128
#define OUT_F 64

// bucketing: node buckets of width 512
#define BW_SHIFT 9
#define BWIDTH 512
#define NB 196              // ceil(100000/512)
#define CB 256              // count/scatter blocks (write-stream count stays CB*NB ~= 50K)
#define EPB (NE / CB)       // 12500 edges per block (divisible by 4)
#define NQ (EPB / 4)        // 3125 int4 per block

// ---------------- phase 1: per-(block,bucket) counts (bucket-major) + wbar/bbar ----------------
// 1024 threads: 4 waves/SIMD so LDS-atomic latency is hidden (R5 was 1 wave/SIMD).
__global__ __launch_bounds__(1024) void count_kernel(const int* __restrict__ src,
                                                     const int* __restrict__ dst,
                                                     int* __restrict__ cntS,
                                                     int* __restrict__ cntD,
                                                     const float* __restrict__ W,
                                                     const float* __restrict__ bias,
                                                     float* __restrict__ wbar,
                                                     float* __restrict__ bbar) {
    __shared__ int hs[NB];
    __shared__ int hd[NB];
    const int blk = blockIdx.x;
    for (int k = threadIdx.x; k < NB; k += 1024) { hs[k] = 0; hd[k] = 0; }
    __syncthreads();
    const int4* s4 = (const int4*)(src + blk * EPB);
    const int4* d4 = (const int4*)(dst + blk * EPB);
    for (int i = threadIdx.x; i < NQ; i += 1024) {
        int4 s = s4[i];
        int4 d = d4[i];
        atomicAdd(&hs[s.x >> BW_SHIFT], 1);
        atomicAdd(&hs[s.y >> BW_SHIFT], 1);
        atomicAdd(&hs[s.z >> BW_SHIFT], 1);
        atomicAdd(&hs[s.w >> BW_SHIFT], 1);
        atomicAdd(&hd[d.x >> BW_SHIFT], 1);
        atomicAdd(&hd[d.y >> BW_SHIFT], 1);
        atomicAdd(&hd[d.z >> BW_SHIFT], 1);
        atomicAdd(&hd[d.w >> BW_SHIFT], 1);
    }
    __syncthreads();
    for (int k = threadIdx.x; k < NB; k += 1024) {
        cntS[k * CB + blk] = hs[k];
        cntD[k * CB + blk] = hd[k];
    }
    // fold wbar/bbar into block 0 (runs concurrently with other blocks' counting)
    if (blk == 0) {
        if (threadIdx.x < IN_F) {
            float s = 0.f;
            for (int j = 0; j < OUT_F; ++j) s += W[threadIdx.x * OUT_F + j];
            wbar[threadIdx.x] = s * (1.0f / OUT_F);
        } else if (threadIdx.x == IN_F) {
            float sb = 0.f;
            for (int j = 0; j < OUT_F; ++j) sb += bias[j];
            *bbar = sb * (1.0f / OUT_F);
        }
    }
}

// ---------------- phase 2a: per-bucket exclusive scan over the 256 block-counts ----------------
__global__ __launch_bounds__(256) void colscan_kernel(int* __restrict__ cntS,
                                                      int* __restrict__ cntD,
                                                      int* __restrict__ colsum) {
    __shared__ int sh[CB];
    const int c = blockIdx.x;
    int* col = (c < NB) ? (cntS + (size_t)c * CB) : (cntD + (size_t)(c - NB) * CB);
    const int t = threadIdx.x;
    int v = col[t];
    sh[t] = v;
    __syncthreads();
    #pragma unroll
    for (int off = 1; off < CB; off <<= 1) {
        int x = (t >= off) ? sh[t - off] : 0;
        __syncthreads();
        sh[t] += x;
        __syncthreads();
    }
    col[t] = sh[t] - v;            // exclusive within-bucket position
    if (t == CB - 1) colsum[c] = sh[t];
}

// ---------------- phase 2b: bucket base offsets ----------------
__global__ __launch_bounds__(256) void basescan_kernel(const int* __restrict__ colsum,
                                                       int* __restrict__ bbaseS,
                                                       int* __restrict__ bbaseD) {
    __shared__ int sh[2 * NB];
    for (int i = threadIdx.x; i < 2 * NB; i += 256) sh[i] = colsum[i];
    __syncthreads();
    if (threadIdx.x == 0) {
        int run = 0;
        for (int k = 0; k < NB; ++k) { bbaseS[k] = run; run += sh[k]; }
        bbaseS[NB] = run;
    }
    if (threadIdx.x == 64) {
        int run = 0;
        for (int k = 0; k < NB; ++k) { bbaseD[k] = run; run += sh[NB + k]; }
        bbaseD[NB] = run;
    }
}

// ---------------- phase 3: scatter into buckets (packed payloads), 1024 threads ----------------
__global__ __launch_bounds__(1024) void scatter_bin_kernel(const int* __restrict__ src,
                                                           const int* __restrict__ dst,
                                                           const int* __restrict__ posS,
                                                           const int* __restrict__ posD,
                                                           const int* __restrict__ bbaseS,
                                                           const int* __restrict__ bbaseD,
                                                           unsigned short* __restrict__ binned_srcloc,
                                                           int* __restrict__ binned_pack) {
    __shared__ int curS[NB];
    __shared__ int curD[NB];
    const int blk = blockIdx.x;
    for (int k = threadIdx.x; k < NB; k += 1024) {
        curS[k] = posS[k * CB + blk] + bbaseS[k];
        curD[k] = posD[k * CB + blk] + bbaseD[k];
    }
    __syncthreads();
    const int4* s4 = (const int4*)(src + blk * EPB);
    const int4* d4 = (const int4*)(dst + blk * EPB);
    for (int i = threadIdx.x; i < NQ; i += 1024) {
        int4 s = s4[i];
        int4 d = d4[i];
        int p;
        p = atomicAdd(&curS[s.x >> BW_SHIFT], 1); binned_srcloc[p] = (unsigned short)(s.x & (BWIDTH - 1));
        p = atomicAdd(&curS[s.y >> BW_SHIFT], 1); binned_srcloc[p] = (unsigned short)(s.y & (BWIDTH - 1));
        p = atomicAdd(&curS[s.z >> BW_SHIFT], 1); binned_srcloc[p] = (unsigned short)(s.z & (BWIDTH - 1));
        p = atomicAdd(&curS[s.w >> BW_SHIFT], 1); binned_srcloc[p] = (unsigned short)(s.w & (BWIDTH - 1));
        // pack: src node id (17 bits) | dst local id (9 bits) << 17
        p = atomicAdd(&curD[d.x >> BW_SHIFT], 1); binned_pack[p] = s.x | ((d.x & (BWIDTH - 1)) << 17);
        p = atomicAdd(&curD[d.y >> BW_SHIFT], 1); binned_pack[p] = s.y | ((d.y & (BWIDTH - 1)) << 17);
        p = atomicAdd(&curD[d.z >> BW_SHIFT], 1); binned_pack[p] = s.z | ((d.z & (BWIDTH - 1)) << 17);
        p = atomicAdd(&curD[d.w >> BW_SHIFT], 1); binned_pack[p] = s.w | ((d.w & (BWIDTH - 1)) << 17);
    }
}

// ---------------- phase 4: out-degree norm per bucket (1024 threads) ----------------
__global__ __launch_bounds__(1024) void degnorm_kernel(const unsigned short* __restrict__ binned_srcloc,
                                                       const int* __restrict__ bbaseS,
                                                       float* __restrict__ out_norm) {
    __shared__ int cnt[BWIDTH];
    const int k = blockIdx.x;
    const int t = threadIdx.x;
    for (int i = t; i < BWIDTH; i += 1024) cnt[i] = 0;
    __syncthreads();
    const int lo = bbaseS[k], hi = bbaseS[k + 1];
    for (int i = lo + t; i < hi; i += 1024) atomicAdd(&cnt[binned_srcloc[i]], 1);
    __syncthreads();
    for (int i = t; i < BWIDTH; i += 1024) {
        int node = (k << BW_SHIFT) + i;
        if (node < NN) out_norm[node] = rsqrtf(fmaxf((float)cnt[i], 1.0f));
    }
}

// ---------------- s[i] = out_norm[i] * dot(features[i], wbar) ----------------
__global__ __launch_bounds__(256) void node_scalar_kernel(const float* __restrict__ features,
                                                          const float* __restrict__ out_norm,
                                                          const float* __restrict__ wbar,
                                                          float* __restrict__ sval) {
    const int lane = threadIdx.x & 63;
    const int wave = threadIdx.x >> 6;
    const int node = blockIdx.x * 4 + wave;
    if (node >= NN) return;
    const float2* f2 = (const float2*)(features + (size_t)node * IN_F);
    const float2* w2 = (const float2*)wbar;
    float2 f = f2[lane];
    float2 w = w2[lane];
    float p = f.x * w.x + f.y * w.y;
    #pragma unroll
    for (int off = 32; off > 0; off >>= 1) p += __shfl_down(p, off);
    if (lane == 0) sval[node] = p * out_norm[node];
}

// ---------------- phase 5: per-bucket accumulate + finalize (1024 threads) ----------------
__global__ __launch_bounds__(1024) void accum_kernel(const int* __restrict__ binned_pack,
                                                     const int* __restrict__ bbaseD,
                                                     const float* __restrict__ sval,
                                                     const float* __restrict__ bbar,
                                                     float* __restrict__ out) {
    __shared__ float agg[BWIDTH];
    __shared__ int cnt[BWIDTH];
    const int k = blockIdx.x;
    const int t = threadIdx.x;
    for (int i = t; i < BWIDTH; i += 1024) { agg[i] = 0.f; cnt[i] = 0; }
    __syncthreads();
    const int lo = bbaseD[k], hi = bbaseD[k + 1];
    for (int i = lo + t; i < hi; i += 1024) {
        int p = binned_pack[i];
        int s = p & 0x1FFFF;
        int loc = (p >> 17) & (BWIDTH - 1);
        float v = sval[s];
        atomicAdd(&agg[loc], v);
        atomicAdd(&cnt[loc], 1);
    }
    __syncthreads();
    for (int i = t; i < BWIDTH; i += 1024) {
        int node = (k << BW_SHIFT) + i;
        if (node < NN) out[node] = agg[i] * rsqrtf(fmaxf((float)cnt[i], 1.0f)) + bbar[0];
    }
}

// ================= fallback (R1 atomic path, needs only ~1.6 MB ws) =================
__global__ void wbar_fb_kernel(const float* __restrict__ W, const float* __restrict__ bias,
                               float* __restrict__ wbar, float* __restrict__ bbar) {
    int k = threadIdx.x;
    float s = 0.f;
    for (int j = 0; j < OUT_F; ++j) s += W[k * OUT_F + j];
    wbar[k] = s * (1.0f / OUT_F);
    if (k == 0) {
        float sb = 0.f;
        for (int j = 0; j < OUT_F; ++j) sb += bias[j];
        *bbar = sb * (1.0f / OUT_F);
    }
}
__global__ void deg_kernel(const int* __restrict__ src, const int* __restrict__ dst,
                           int* __restrict__ deg_out, int* __restrict__ deg_in) {
    const int nq = NE / 4;
    int i = blockIdx.x * blockDim.x + threadIdx.x;
    const int stride = gridDim.x * blockDim.x;
    const int4* src4 = (const int4*)src;
    const int4* dst4 = (const int4*)dst;
    for (; i < nq; i += stride) {
        int4 s = src4[i];
        int4 d = dst4[i];
        atomicAdd(&deg_out[s.x], 1); atomicAdd(&deg_out[s.y], 1);
        atomicAdd(&deg_out[s.z], 1); atomicAdd(&deg_out[s.w], 1);
        atomicAdd(&deg_in[d.x], 1);  atomicAdd(&deg_in[d.y], 1);
        atomicAdd(&deg_in[d.z], 1);  atomicAdd(&deg_in[d.w], 1);
    }
}
__global__ void node_scalar_deg_kernel(const float* __restrict__ features,
                                       const int* __restrict__ deg_out,
                                       const float* __restrict__ wbar,
                                       float* __restrict__ sval) {
    const int lane = threadIdx.x & 63;
    const int wave = threadIdx.x >> 6;
    const int node = blockIdx.x * 4 + wave;
    if (node >= NN) return;
    const float2* f2 = (const float2*)(features + (size_t)node * IN_F);
    const float2* w2 = (const float2*)wbar;
    float2 f = f2[lane];
    float2 w = w2[lane];
    float p = f.x * w.x + f.y * w.y;
    #pragma unroll
    for (int off = 32; off > 0; off >>= 1) p += __shfl_down(p, off);
    if (lane == 0) {
        float d = (float)deg_out[node];
        sval[node] = p * rsqrtf(fmaxf(d, 1.0f));
    }
}
__global__ void scatter_kernel(const int* __restrict__ src, const int* __restrict__ dst,
                               const float* __restrict__ sval, float* __restrict__ agg) {
    const int nq = NE / 4;
    int i = blockIdx.x * blockDim.x + threadIdx.x;
    const int stride = gridDim.x * blockDim.x;
    const int4* src4 = (const int4*)src;
    const int4* dst4 = (const int4*)dst;
    for (; i < nq; i += stride) {
        int4 s = src4[i];
        int4 d = dst4[i];
        atomicAdd(&agg[d.x], sval[s.x]);
        atomicAdd(&agg[d.y], sval[s.y]);
        atomicAdd(&agg[d.z], sval[s.z]);
        atomicAdd(&agg[d.w], sval[s.w]);
    }
}
__global__ void final_kernel(const float* __restrict__ agg, const int* __restrict__ deg_in,
                             const float* __restrict__ bbar, float* __restrict__ out) {
    int n = blockIdx.x * blockDim.x + threadIdx.x;
    if (n >= NN) return;
    float d = (float)deg_in[n];
    out[n] = agg[n] * rsqrtf(fmaxf(d, 1.0f)) + *bbar;
}

extern "C" void kernel_launch(void* const* d_in, const int* in_sizes, int n_in,
                              void* d_out, int out_size, void* d_ws, size_t ws_size,
                              hipStream_t stream) {
    const float* features = (const float*)d_in[0];
    const float* W        = (const float*)d_in[1];
    const float* bias     = (const float*)d_in[2];
    const int*   src      = (const int*)d_in[3];
    const int*   dst      = (const int*)d_in[4];
    float* out = (float*)d_out;

    // fast-path workspace layout (4-byte words):
    // [0, NE)              binned_pack (int)
    // [NE, NE+NE/2)        binned_srcloc (ushort[NE])
    // [+NB*CB]             cntS/posS
    // [+NB*CB]             cntD/posD
    // [+2*NB]              colsum
    // [+NB+1]              bbaseS
    // [+NB+1]              bbaseD
    // [+NN]                out_norm
    // [+NN]                sval
    // [+128]               wbar
    // [+1]                 bbar
    size_t need_words = (size_t)NE + NE / 2 + 2 * (size_t)NB * CB + 2 * NB + 2 * (NB + 1)
                      + 2 * (size_t)NN + IN_F + 1;
    if (ws_size >= need_words * 4 + 64) {
        int* w_ = (int*)d_ws;
        int*  binned_pack          = w_;
        unsigned short* binned_srcloc = (unsigned short*)(w_ + NE);
        int*  cntS        = w_ + NE + NE / 2;
        int*  cntD        = cntS + (size_t)NB * CB;
        int*  colsum      = cntD + (size_t)NB * CB;
        int*  bbaseS      = colsum + 2 * NB;
        int*  bbaseD      = bbaseS + (NB + 1);
        float* out_norm   = (float*)(bbaseD + (NB + 1));
        float* sval       = out_norm + NN;
        float* wbar       = sval + NN;
        float* bbar       = wbar + IN_F;

        count_kernel<<<CB, 1024, 0, stream>>>(src, dst, cntS, cntD, W, bias, wbar, bbar);
        colscan_kernel<<<2 * NB, 256, 0, stream>>>(cntS, cntD, colsum);
        basescan_kernel<<<1, 256, 0, stream>>>(colsum, bbaseS, bbaseD);
        scatter_bin_kernel<<<CB, 1024, 0, stream>>>(src, dst, cntS, cntD, bbaseS, bbaseD,
                                                    binned_srcloc, binned_pack);
        degnorm_kernel<<<NB, 1024, 0, stream>>>(binned_srcloc, bbaseS, out_norm);
        node_scalar_kernel<<<(NN + 3) / 4, 256, 0, stream>>>(features, out_norm, wbar, sval);
        accum_kernel<<<NB, 1024, 0, stream>>>(binned_pack, bbaseD, sval, bbar, out);
    } else {
        // fallback: R1 atomic path
        int*   deg_out = (int*)d_ws;
        int*   deg_in  = deg_out + NN;
        float* agg     = (float*)(deg_in + NN);
        float* sval    = agg + NN;
        float* wbar    = sval + NN;
        float* bbar    = wbar + IN_F;
        hipMemsetAsync(d_ws, 0, (size_t)3 * NN * sizeof(int), stream);
        wbar_fb_kernel<<<1, 128, 0, stream>>>(W, bias, wbar, bbar);
        deg_kernel<<<2048, 256, 0, stream>>>(src, dst, deg_out, deg_in);
        node_scalar_deg_kernel<<<(NN + 3) / 4, 256, 0, stream>>>(features, deg_out, wbar, sval);
        scatter_kernel<<<2048, 256, 0, stream>>>(src, dst, sval, agg);
        final_kernel<<<(NN + 255) / 256, 256, 0, stream>>>(agg, deg_in, bbar, out);
    }
}

// Round 7
// 189.687 us; speedup vs baseline: 2.8000x; 1.0189x over previous
//
#include <hip/hip_runtime.h>

#define NN 100000
#define NE 3200000
#define IN_F 128
#define OUT_F 64

#define BW_SHIFT 9
#define BWIDTH 512
#define NB 196              // ceil(100000/512)
#define CAP 20480           // per-bucket slot capacity; mean 16326, +32 sigma safe
#define CB 256              // bin blocks
#define EPB (NE / CB)       // 12500 edges per block
#define NQ (EPB / 4)        // 3125 int4 per block

// ---------------- phase 1: fused count + reserve + scatter (+ wbar in block 0) ----------------
__global__ __launch_bounds__(1024) void bin_kernel(const int* __restrict__ src,
                                                   const int* __restrict__ dst,
                                                   int* __restrict__ curS_g,
                                                   int* __restrict__ curD_g,
                                                   unsigned short* __restrict__ srcloc,
                                                   int* __restrict__ pack,
                                                   const float* __restrict__ W,
                                                   const float* __restrict__ bias,
                                                   float* __restrict__ wbar,
                                                   float* __restrict__ bbar) {
    __shared__ int hs[NB];
    __shared__ int hd[NB];
    __shared__ int cS[NB];
    __shared__ int cD[NB];
    const int blk = blockIdx.x;
    const int t = threadIdx.x;
    for (int k = t; k < NB; k += 1024) { hs[k] = 0; hd[k] = 0; }
    __syncthreads();

    const int4* s4 = (const int4*)(src + blk * EPB);
    const int4* d4 = (const int4*)(dst + blk * EPB);
    // cache this block's edge chunk in registers (static indexing -> no scratch)
    int4 sc[4], dc[4];
    #pragma unroll
    for (int u = 0; u < 4; ++u) {
        int i = t + u * 1024;
        if (i < NQ) { sc[u] = s4[i]; dc[u] = d4[i]; }
        else        { sc[u] = make_int4(-1, -1, -1, -1); dc[u] = sc[u]; }
    }
    // pass 1: local histogram
    #pragma unroll
    for (int u = 0; u < 4; ++u) {
        if (sc[u].x >= 0) {
            atomicAdd(&hs[sc[u].x >> BW_SHIFT], 1);
            atomicAdd(&hs[sc[u].y >> BW_SHIFT], 1);
            atomicAdd(&hs[sc[u].z >> BW_SHIFT], 1);
            atomicAdd(&hs[sc[u].w >> BW_SHIFT], 1);
            atomicAdd(&hd[dc[u].x >> BW_SHIFT], 1);
            atomicAdd(&hd[dc[u].y >> BW_SHIFT], 1);
            atomicAdd(&hd[dc[u].z >> BW_SHIFT], 1);
            atomicAdd(&hd[dc[u].w >> BW_SHIFT], 1);
        }
    }
    __syncthreads();
    // reserve contiguous ranges in each bucket (one global atomic per (block,bucket))
    for (int k = t; k < NB; k += 1024) {
        cS[k] = k * CAP + atomicAdd(&curS_g[k], hs[k]);
        cD[k] = k * CAP + atomicAdd(&curD_g[k], hd[k]);
    }
    __syncthreads();
    // pass 2: scatter from registers into reserved ranges
    #pragma unroll
    for (int u = 0; u < 4; ++u) {
        if (sc[u].x >= 0) {
            int p;
            p = atomicAdd(&cS[sc[u].x >> BW_SHIFT], 1); srcloc[p] = (unsigned short)(sc[u].x & (BWIDTH - 1));
            p = atomicAdd(&cS[sc[u].y >> BW_SHIFT], 1); srcloc[p] = (unsigned short)(sc[u].y & (BWIDTH - 1));
            p = atomicAdd(&cS[sc[u].z >> BW_SHIFT], 1); srcloc[p] = (unsigned short)(sc[u].z & (BWIDTH - 1));
            p = atomicAdd(&cS[sc[u].w >> BW_SHIFT], 1); srcloc[p] = (unsigned short)(sc[u].w & (BWIDTH - 1));
            // pack: src node id (17 bits) | dst local id (9 bits) << 17
            p = atomicAdd(&cD[dc[u].x >> BW_SHIFT], 1); pack[p] = sc[u].x | ((dc[u].x & (BWIDTH - 1)) << 17);
            p = atomicAdd(&cD[dc[u].y >> BW_SHIFT], 1); pack[p] = sc[u].y | ((dc[u].y & (BWIDTH - 1)) << 17);
            p = atomicAdd(&cD[dc[u].z >> BW_SHIFT], 1); pack[p] = sc[u].z | ((dc[u].z & (BWIDTH - 1)) << 17);
            p = atomicAdd(&cD[dc[u].w >> BW_SHIFT], 1); pack[p] = sc[u].w | ((dc[u].w & (BWIDTH - 1)) << 17);
        }
    }
    // fold wbar/bbar into block 0
    if (blk == 0) {
        if (t < IN_F) {
            float s = 0.f;
            for (int j = 0; j < OUT_F; ++j) s += W[t * OUT_F + j];
            wbar[t] = s * (1.0f / OUT_F);
        } else if (t == IN_F) {
            float sb = 0.f;
            for (int j = 0; j < OUT_F; ++j) sb += bias[j];
            *bbar = sb * (1.0f / OUT_F);
        }
    }
}

// ---------------- phase 2: fused degnorm + node_scalar per src-bucket ----------------
__global__ __launch_bounds__(1024) void bucket_scalar_kernel(const unsigned short* __restrict__ srcloc,
                                                             const int* __restrict__ curS_g,
                                                             const float* __restrict__ features,
                                                             const float* __restrict__ wbar,
                                                             float* __restrict__ sval) {
    __shared__ int cnt[BWIDTH];
    __shared__ float wsh[IN_F];
    const int k = blockIdx.x;
    const int t = threadIdx.x;
    if (t < IN_F) wsh[t] = wbar[t];
    for (int i = t; i < BWIDTH; i += 1024) cnt[i] = 0;
    __syncthreads();
    const int base = k * CAP;
    const int len = curS_g[k];
    for (int i = t; i < len; i += 1024) atomicAdd(&cnt[srcloc[base + i]], 1);
    __syncthreads();
    const int lane = t & 63;
    const int wave = t >> 6;          // 16 waves, 32 nodes each
    const float2 w = ((const float2*)wsh)[lane];
    for (int j = 0; j < 32; ++j) {
        const int loc = wave * 32 + j;
        const int node = (k << BW_SHIFT) + loc;
        if (node >= NN) break;
        float2 f = ((const float2*)(features + (size_t)node * IN_F))[lane];
        float p = f.x * w.x + f.y * w.y;
        #pragma unroll
        for (int off = 32; off > 0; off >>= 1) p += __shfl_down(p, off);
        if (lane == 0) sval[node] = p * rsqrtf(fmaxf((float)cnt[loc], 1.0f));
    }
}

// ---------------- phase 3: per-dst-bucket accumulate + finalize ----------------
__global__ __launch_bounds__(1024) void accum_kernel(const int* __restrict__ pack,
                                                     const int* __restrict__ curD_g,
                                                     const float* __restrict__ sval,
                                                     const float* __restrict__ bbar,
                                                     float* __restrict__ out) {
    __shared__ float agg[BWIDTH];
    __shared__ int cnt[BWIDTH];
    const int k = blockIdx.x;
    const int t = threadIdx.x;
    for (int i = t; i < BWIDTH; i += 1024) { agg[i] = 0.f; cnt[i] = 0; }
    __syncthreads();
    const int base = k * CAP;
    const int len = curD_g[k];
    for (int i = t; i < len; i += 1024) {
        int p = pack[base + i];
        int s = p & 0x1FFFF;
        int loc = (p >> 17) & (BWIDTH - 1);
        float v = sval[s];
        atomicAdd(&agg[loc], v);
        atomicAdd(&cnt[loc], 1);
    }
    __syncthreads();
    for (int i = t; i < BWIDTH; i += 1024) {
        int node = (k << BW_SHIFT) + i;
        if (node < NN) out[node] = agg[i] * rsqrtf(fmaxf((float)cnt[i], 1.0f)) + bbar[0];
    }
}

// ================= fallback (R1 atomic path, needs only ~1.6 MB ws) =================
__global__ void wbar_fb_kernel(const float* __restrict__ W, const float* __restrict__ bias,
                               float* __restrict__ wbar, float* __restrict__ bbar) {
    int k = threadIdx.x;
    float s = 0.f;
    for (int j = 0; j < OUT_F; ++j) s += W[k * OUT_F + j];
    wbar[k] = s * (1.0f / OUT_F);
    if (k == 0) {
        float sb = 0.f;
        for (int j = 0; j < OUT_F; ++j) sb += bias[j];
        *bbar = sb * (1.0f / OUT_F);
    }
}
__global__ void deg_kernel(const int* __restrict__ src, const int* __restrict__ dst,
                           int* __restrict__ deg_out, int* __restrict__ deg_in) {
    const int nq = NE / 4;
    int i = blockIdx.x * blockDim.x + threadIdx.x;
    const int stride = gridDim.x * blockDim.x;
    const int4* src4 = (const int4*)src;
    const int4* dst4 = (const int4*)dst;
    for (; i < nq; i += stride) {
        int4 s = src4[i];
        int4 d = dst4[i];
        atomicAdd(&deg_out[s.x], 1); atomicAdd(&deg_out[s.y], 1);
        atomicAdd(&deg_out[s.z], 1); atomicAdd(&deg_out[s.w], 1);
        atomicAdd(&deg_in[d.x], 1);  atomicAdd(&deg_in[d.y], 1);
        atomicAdd(&deg_in[d.z], 1);  atomicAdd(&deg_in[d.w], 1);
    }
}
__global__ void node_scalar_deg_kernel(const float* __restrict__ features,
                                       const int* __restrict__ deg_out,
                                       const float* __restrict__ wbar,
                                       float* __restrict__ sval) {
    const int lane = threadIdx.x & 63;
    const int wave = threadIdx.x >> 6;
    const int node = blockIdx.x * 4 + wave;
    if (node >= NN) return;
    const float2* f2 = (const float2*)(features + (size_t)node * IN_F);
    const float2* w2 = (const float2*)wbar;
    float2 f = f2[lane];
    float2 w = w2[lane];
    float p = f.x * w.x + f.y * w.y;
    #pragma unroll
    for (int off = 32; off > 0; off >>= 1) p += __shfl_down(p, off);
    if (lane == 0) {
        float d = (float)deg_out[node];
        sval[node] = p * rsqrtf(fmaxf(d, 1.0f));
    }
}
__global__ void scatter_kernel(const int* __restrict__ src, const int* __restrict__ dst,
                               const float* __restrict__ sval, float* __restrict__ agg) {
    const int nq = NE / 4;
    int i = blockIdx.x * blockDim.x + threadIdx.x;
    const int stride = gridDim.x * blockDim.x;
    const int4* src4 = (const int4*)src;
    const int4* dst4 = (const int4*)dst;
    for (; i < nq; i += stride) {
        int4 s = src4[i];
        int4 d = dst4[i];
        atomicAdd(&agg[d.x], sval[s.x]);
        atomicAdd(&agg[d.y], sval[s.y]);
        atomicAdd(&agg[d.z], sval[s.z]);
        atomicAdd(&agg[d.w], sval[s.w]);
    }
}
__global__ void final_kernel(const float* __restrict__ agg, const int* __restrict__ deg_in,
                             const float* __restrict__ bbar, float* __restrict__ out) {
    int n = blockIdx.x * blockDim.x + threadIdx.x;
    if (n >= NN) return;
    float d = (float)deg_in[n];
    out[n] = agg[n] * rsqrtf(fmaxf(d, 1.0f)) + *bbar;
}

extern "C" void kernel_launch(void* const* d_in, const int* in_sizes, int n_in,
                              void* d_out, int out_size, void* d_ws, size_t ws_size,
                              hipStream_t stream) {
    const float* features = (const float*)d_in[0];
    const float* W        = (const float*)d_in[1];
    const float* bias     = (const float*)d_in[2];
    const int*   src      = (const int*)d_in[3];
    const int*   dst      = (const int*)d_in[4];
    float* out = (float*)d_out;

    // fast-path workspace layout (4-byte words):
    // [0, NB*CAP)            pack (int)
    // [+NB*CAP/2]            srcloc (ushort[NB*CAP])
    // [+NB]                  curS
    // [+NB]                  curD
    // [+NN]                  sval
    // [+IN_F]                wbar
    // [+1]                   bbar
    size_t need_words = (size_t)NB * CAP + (size_t)NB * CAP / 2 + 2 * NB
                      + (size_t)NN + IN_F + 1;
    if (ws_size >= need_words * 4 + 64) {
        int* w_ = (int*)d_ws;
        int*  pack              = w_;
        unsigned short* srcloc  = (unsigned short*)(w_ + (size_t)NB * CAP);
        int*  curS_g            = w_ + (size_t)NB * CAP + (size_t)NB * CAP / 2;
        int*  curD_g            = curS_g + NB;
        float* sval             = (float*)(curD_g + NB);
        float* wbar             = sval + NN;
        float* bbar             = wbar + IN_F;

        hipMemsetAsync(curS_g, 0, 2 * NB * sizeof(int), stream);
        bin_kernel<<<CB, 1024, 0, stream>>>(src, dst, curS_g, curD_g, srcloc, pack,
                                            W, bias, wbar, bbar);
        bucket_scalar_kernel<<<NB, 1024, 0, stream>>>(srcloc, curS_g, features, wbar, sval);
        accum_kernel<<<NB, 1024, 0, stream>>>(pack, curD_g, sval, bbar, out);
    } else {
        // fallback: R1 atomic path
        int*   deg_out = (int*)d_ws;
        int*   deg_in  = deg_out + NN;
        float* agg     = (float*)(deg_in + NN);
        float* sval    = agg + NN;
        float* wbar    = sval + NN;
        float* bbar    = wbar + IN_F;
        hipMemsetAsync(d_ws, 0, (size_t)3 * NN * sizeof(int), stream);
        wbar_fb_kernel<<<1, 128, 0, stream>>>(W, bias, wbar, bbar);
        deg_kernel<<<2048, 256, 0, stream>>>(src, dst, deg_out, deg_in);
        node_scalar_deg_kernel<<<(NN + 3) / 4, 256, 0, stream>>>(features, deg_out, wbar, sval);
        scatter_kernel<<<2048, 256, 0, stream>>>(src, dst, sval, agg);
        final_kernel<<<(NN + 255) / 256, 256, 0, stream>>>(agg, deg_in, bbar, out);
    }
}

// Round 8
// 159.247 us; speedup vs baseline: 3.3352x; 1.1911x over previous
//
#include <hip/hip_runtime.h>

#define NN 100000
#define NE 3200000
#define IN_F 128
#define OUT_F 64

#define BW_SHIFT 9
#define BWIDTH 512
#define NB 196              // ceil(100000/512)
#define CAP 20480           // per-bucket slot capacity; mean 16384, +32 sigma safe
#define CB 256              // bin blocks
#define EPB (NE / CB)       // 12500 edges per block
#define NQ (EPB / 4)        // 3125 int4 per block

// ---------------- phase 1: fused count + local sort + coalesced scatter ----------------
// LDS-staged counting sort per block: all global writes are contiguous per bucket segment.
__global__ __launch_bounds__(1024) void bin_kernel(const int* __restrict__ src,
                                                   const int* __restrict__ dst,
                                                   int* __restrict__ curS_g,
                                                   int* __restrict__ curD_g,
                                                   unsigned short* __restrict__ srcloc,
                                                   int* __restrict__ pack,
                                                   const float* __restrict__ W,
                                                   const float* __restrict__ bias,
                                                   float* __restrict__ wbar,
                                                   float* __restrict__ bbar) {
    __shared__ int hs[NB], hd[NB];          // per-bucket counts
    __shared__ int lS[NB], lD[NB];          // local exclusive prefix (segment starts in staging)
    __shared__ int cS[NB], cD[NB];          // scatter cursors
    __shared__ int gS[NB], gD[NB];          // reserved global bases
    __shared__ int scanbuf[256];
    __shared__ unsigned short stS[EPB];     // 25000 B staging (srcloc)
    __shared__ int stD[EPB];                // 50000 B staging (pack)
    const int blk = blockIdx.x;
    const int t = threadIdx.x;
    for (int k = t; k < NB; k += 1024) { hs[k] = 0; hd[k] = 0; }
    __syncthreads();

    const int4* s4 = (const int4*)(src + blk * EPB);
    const int4* d4 = (const int4*)(dst + blk * EPB);
    // cache chunk in registers (static indexing)
    int4 sc[4], dc[4];
    #pragma unroll
    for (int u = 0; u < 4; ++u) {
        int i = t + u * 1024;
        if (i < NQ) { sc[u] = s4[i]; dc[u] = d4[i]; }
        else        { sc[u] = make_int4(-1, -1, -1, -1); dc[u] = sc[u]; }
    }
    // pass 1: histogram
    #pragma unroll
    for (int u = 0; u < 4; ++u) {
        if (sc[u].x >= 0) {
            atomicAdd(&hs[sc[u].x >> BW_SHIFT], 1);
            atomicAdd(&hs[sc[u].y >> BW_SHIFT], 1);
            atomicAdd(&hs[sc[u].z >> BW_SHIFT], 1);
            atomicAdd(&hs[sc[u].w >> BW_SHIFT], 1);
            atomicAdd(&hd[dc[u].x >> BW_SHIFT], 1);
            atomicAdd(&hd[dc[u].y >> BW_SHIFT], 1);
            atomicAdd(&hd[dc[u].z >> BW_SHIFT], 1);
            atomicAdd(&hd[dc[u].w >> BW_SHIFT], 1);
        }
    }
    __syncthreads();
    // local exclusive prefix over buckets: S side
    if (t < 256) scanbuf[t] = (t < NB) ? hs[t] : 0;
    __syncthreads();
    #pragma unroll
    for (int off = 1; off < 256; off <<= 1) {
        int x = (t < 256 && t >= off) ? scanbuf[t - off] : 0;
        __syncthreads();
        if (t < 256) scanbuf[t] += x;
        __syncthreads();
    }
    if (t < NB) { int e = scanbuf[t] - hs[t]; lS[t] = e; cS[t] = e; }
    __syncthreads();
    // D side (reuse scanbuf)
    if (t < 256) scanbuf[t] = (t < NB) ? hd[t] : 0;
    __syncthreads();
    #pragma unroll
    for (int off = 1; off < 256; off <<= 1) {
        int x = (t < 256 && t >= off) ? scanbuf[t - off] : 0;
        __syncthreads();
        if (t < 256) scanbuf[t] += x;
        __syncthreads();
    }
    if (t < NB) { int e = scanbuf[t] - hd[t]; lD[t] = e; cD[t] = e; }
    // reserve global segments (one atomic per (block,bucket))
    if (t < NB) {
        gS[t] = t * CAP + atomicAdd(&curS_g[t], hs[t]);
        gD[t] = t * CAP + atomicAdd(&curD_g[t], hd[t]);
    }
    __syncthreads();
    // pass 2: scatter into LDS staging (sorted by bucket)
    #pragma unroll
    for (int u = 0; u < 4; ++u) {
        if (sc[u].x >= 0) {
            int p;
            p = atomicAdd(&cS[sc[u].x >> BW_SHIFT], 1); stS[p] = (unsigned short)(sc[u].x & (BWIDTH - 1));
            p = atomicAdd(&cS[sc[u].y >> BW_SHIFT], 1); stS[p] = (unsigned short)(sc[u].y & (BWIDTH - 1));
            p = atomicAdd(&cS[sc[u].z >> BW_SHIFT], 1); stS[p] = (unsigned short)(sc[u].z & (BWIDTH - 1));
            p = atomicAdd(&cS[sc[u].w >> BW_SHIFT], 1); stS[p] = (unsigned short)(sc[u].w & (BWIDTH - 1));
            // pack: src node id (17 bits) | dst local id (9 bits) << 17
            p = atomicAdd(&cD[dc[u].x >> BW_SHIFT], 1); stD[p] = sc[u].x | ((dc[u].x & (BWIDTH - 1)) << 17);
            p = atomicAdd(&cD[dc[u].y >> BW_SHIFT], 1); stD[p] = sc[u].y | ((dc[u].y & (BWIDTH - 1)) << 17);
            p = atomicAdd(&cD[dc[u].z >> BW_SHIFT], 1); stD[p] = sc[u].z | ((dc[u].z & (BWIDTH - 1)) << 17);
            p = atomicAdd(&cD[dc[u].w >> BW_SHIFT], 1); stD[p] = sc[u].w | ((dc[u].w & (BWIDTH - 1)) << 17);
        }
    }
    __syncthreads();
    // pass 3: coalesced copy-out, wave per bucket
    const int wv = t >> 6, ln = t & 63;
    for (int k = wv; k < NB; k += 16) {
        int len = hs[k], lb = lS[k], gb = gS[k];
        for (int j = ln; j < len; j += 64) srcloc[gb + j] = stS[lb + j];
        len = hd[k]; lb = lD[k]; gb = gD[k];
        for (int j = ln; j < len; j += 64) pack[gb + j] = stD[lb + j];
    }
    // fold wbar/bbar into block 0
    if (blk == 0) {
        if (t < IN_F) {
            float s = 0.f;
            for (int j = 0; j < OUT_F; ++j) s += W[t * OUT_F + j];
            wbar[t] = s * (1.0f / OUT_F);
        } else if (t == IN_F) {
            float sb = 0.f;
            for (int j = 0; j < OUT_F; ++j) sb += bias[j];
            *bbar = sb * (1.0f / OUT_F);
        }
    }
}

// ---------------- phase 2: fused degnorm + node dot per src-bucket ----------------
__global__ __launch_bounds__(1024) void bucket_scalar_kernel(const unsigned short* __restrict__ srcloc,
                                                             const int* __restrict__ curS_g,
                                                             const float* __restrict__ features,
                                                             const float* __restrict__ wbar,
                                                             float* __restrict__ sval) {
    __shared__ int cnt[BWIDTH];
    __shared__ float4 wsh[IN_F / 4];
    const int k = blockIdx.x;
    const int t = threadIdx.x;
    if (t < IN_F / 4) wsh[t] = ((const float4*)wbar)[t];
    for (int i = t; i < BWIDTH; i += 1024) cnt[i] = 0;
    __syncthreads();
    const int base = k * CAP;
    const int len = curS_g[k];
    for (int i = t; i < len; i += 1024) atomicAdd(&cnt[srcloc[base + i]], 1);
    __syncthreads();
    // 16-lane groups, 4 nodes per wave in flight, 8 iterations
    const int wv = t >> 6, ln = t & 63;
    const int sub = ln >> 4, sl = ln & 15;
    const float4 wa = wsh[sl], wb = wsh[sl + 16];
    #pragma unroll
    for (int it = 0; it < 8; ++it) {
        const int loc = (wv << 5) + (it << 2) + sub;
        const int node = (k << BW_SHIFT) + loc;
        if (node < NN) {
            const float4* f4 = (const float4*)(features + (size_t)node * IN_F);
            float4 fa = f4[sl], fb = f4[sl + 16];
            float p = fa.x * wa.x + fa.y * wa.y + fa.z * wa.z + fa.w * wa.w
                    + fb.x * wb.x + fb.y * wb.y + fb.z * wb.z + fb.w * wb.w;
            #pragma unroll
            for (int off = 1; off < 16; off <<= 1) p += __shfl_xor(p, off);
            if (sl == 0) sval[node] = p * rsqrtf(fmaxf((float)cnt[loc], 1.0f));
        }
    }
}

// ---------------- phase 3: per-dst-bucket accumulate + finalize ----------------
__global__ __launch_bounds__(1024) void accum_kernel(const int* __restrict__ pack,
                                                     const int* __restrict__ curD_g,
                                                     const float* __restrict__ sval,
                                                     const float* __restrict__ bbar,
                                                     float* __restrict__ out) {
    __shared__ float agg[BWIDTH];
    __shared__ int cnt[BWIDTH];
    const int k = blockIdx.x;
    const int t = threadIdx.x;
    for (int i = t; i < BWIDTH; i += 1024) { agg[i] = 0.f; cnt[i] = 0; }
    __syncthreads();
    const int base = k * CAP;
    const int len = curD_g[k];
    for (int i = t; i < len; i += 1024) {
        int p = pack[base + i];
        int s = p & 0x1FFFF;
        int loc = (p >> 17) & (BWIDTH - 1);
        float v = sval[s];
        atomicAdd(&agg[loc], v);
        atomicAdd(&cnt[loc], 1);
    }
    __syncthreads();
    for (int i = t; i < BWIDTH; i += 1024) {
        int node = (k << BW_SHIFT) + i;
        if (node < NN) out[node] = agg[i] * rsqrtf(fmaxf((float)cnt[i], 1.0f)) + bbar[0];
    }
}

// ================= fallback (R1 atomic path, needs only ~1.6 MB ws) =================
__global__ void wbar_fb_kernel(const float* __restrict__ W, const float* __restrict__ bias,
                               float* __restrict__ wbar, float* __restrict__ bbar) {
    int k = threadIdx.x;
    float s = 0.f;
    for (int j = 0; j < OUT_F; ++j) s += W[k * OUT_F + j];
    wbar[k] = s * (1.0f / OUT_F);
    if (k == 0) {
        float sb = 0.f;
        for (int j = 0; j < OUT_F; ++j) sb += bias[j];
        *bbar = sb * (1.0f / OUT_F);
    }
}
__global__ void deg_kernel(const int* __restrict__ src, const int* __restrict__ dst,
                           int* __restrict__ deg_out, int* __restrict__ deg_in) {
    const int nq = NE / 4;
    int i = blockIdx.x * blockDim.x + threadIdx.x;
    const int stride = gridDim.x * blockDim.x;
    const int4* src4 = (const int4*)src;
    const int4* dst4 = (const int4*)dst;
    for (; i < nq; i += stride) {
        int4 s = src4[i];
        int4 d = dst4[i];
        atomicAdd(&deg_out[s.x], 1); atomicAdd(&deg_out[s.y], 1);
        atomicAdd(&deg_out[s.z], 1); atomicAdd(&deg_out[s.w], 1);
        atomicAdd(&deg_in[d.x], 1);  atomicAdd(&deg_in[d.y], 1);
        atomicAdd(&deg_in[d.z], 1);  atomicAdd(&deg_in[d.w], 1);
    }
}
__global__ void node_scalar_deg_kernel(const float* __restrict__ features,
                                       const int* __restrict__ deg_out,
                                       const float* __restrict__ wbar,
                                       float* __restrict__ sval) {
    const int lane = threadIdx.x & 63;
    const int wave = threadIdx.x >> 6;
    const int node = blockIdx.x * 4 + wave;
    if (node >= NN) return;
    const float2* f2 = (const float2*)(features + (size_t)node * IN_F);
    const float2* w2 = (const float2*)wbar;
    float2 f = f2[lane];
    float2 w = w2[lane];
    float p = f.x * w.x + f.y * w.y;
    #pragma unroll
    for (int off = 32; off > 0; off >>= 1) p += __shfl_down(p, off);
    if (lane == 0) {
        float d = (float)deg_out[node];
        sval[node] = p * rsqrtf(fmaxf(d, 1.0f));
    }
}
__global__ void scatter_kernel(const int* __restrict__ src, const int* __restrict__ dst,
                               const float* __restrict__ sval, float* __restrict__ agg) {
    const int nq = NE / 4;
    int i = blockIdx.x * blockDim.x + threadIdx.x;
    const int stride = gridDim.x * blockDim.x;
    const int4* src4 = (const int4*)src;
    const int4* dst4 = (const int4*)dst;
    for (; i < nq; i += stride) {
        int4 s = src4[i];
        int4 d = dst4[i];
        atomicAdd(&agg[d.x], sval[s.x]);
        atomicAdd(&agg[d.y], sval[s.y]);
        atomicAdd(&agg[d.z], sval[s.z]);
        atomicAdd(&agg[d.w], sval[s.w]);
    }
}
__global__ void final_kernel(const float* __restrict__ agg, const int* __restrict__ deg_in,
                             const float* __restrict__ bbar, float* __restrict__ out) {
    int n = blockIdx.x * blockDim.x + threadIdx.x;
    if (n >= NN) return;
    float d = (float)deg_in[n];
    out[n] = agg[n] * rsqrtf(fmaxf(d, 1.0f)) + *bbar;
}

extern "C" void kernel_launch(void* const* d_in, const int* in_sizes, int n_in,
                              void* d_out, int out_size, void* d_ws, size_t ws_size,
                              hipStream_t stream) {
    const float* features = (const float*)d_in[0];
    const float* W        = (const float*)d_in[1];
    const float* bias     = (const float*)d_in[2];
    const int*   src      = (const int*)d_in[3];
    const int*   dst      = (const int*)d_in[4];
    float* out = (float*)d_out;

    // fast-path workspace layout (4-byte words):
    // [0, NB*CAP)            pack (int)
    // [+NB*CAP/2]            srcloc (ushort[NB*CAP])
    // [+NB]                  curS
    // [+NB]                  curD
    // [+NN]                  sval
    // [+IN_F]                wbar
    // [+1]                   bbar
    size_t need_words = (size_t)NB * CAP + (size_t)NB * CAP / 2 + 2 * NB
                      + (size_t)NN + IN_F + 1;
    if (ws_size >= need_words * 4 + 64) {
        int* w_ = (int*)d_ws;
        int*  pack              = w_;
        unsigned short* srcloc  = (unsigned short*)(w_ + (size_t)NB * CAP);
        int*  curS_g            = w_ + (size_t)NB * CAP + (size_t)NB * CAP / 2;
        int*  curD_g            = curS_g + NB;
        float* sval             = (float*)(curD_g + NB);
        float* wbar             = sval + NN;
        float* bbar             = wbar + IN_F;

        hipMemsetAsync(curS_g, 0, 2 * NB * sizeof(int), stream);
        bin_kernel<<<CB, 1024, 0, stream>>>(src, dst, curS_g, curD_g, srcloc, pack,
                                            W, bias, wbar, bbar);
        bucket_scalar_kernel<<<NB, 1024, 0, stream>>>(srcloc, curS_g, features, wbar, sval);
        accum_kernel<<<NB, 1024, 0, stream>>>(pack, curD_g, sval, bbar, out);
    } else {
        // fallback: R1 atomic path
        int*   deg_out = (int*)d_ws;
        int*   deg_in  = deg_out + NN;
        float* agg     = (float*)(deg_in + NN);
        float* sval    = agg + NN;
        float* wbar    = sval + NN;
        float* bbar    = wbar + IN_F;
        hipMemsetAsync(d_ws, 0, (size_t)3 * NN * sizeof(int), stream);
        wbar_fb_kernel<<<1, 128, 0, stream>>>(W, bias, wbar, bbar);
        deg_kernel<<<2048, 256, 0, stream>>>(src, dst, deg_out, deg_in);
        node_scalar_deg_kernel<<<(NN + 3) / 4, 256, 0, stream>>>(features, deg_out, wbar, sval);
        scatter_kernel<<<2048, 256, 0, stream>>>(src, dst, sval, agg);
        final_kernel<<<(NN + 255) / 256, 256, 0, stream>>>(agg, deg_in, bbar, out);
    }
}

// Round 9
// 158.310 us; speedup vs baseline: 3.3550x; 1.0059x over previous
//
#include <hip/hip_runtime.h>

#define NN 100000
#define NE 3200000
#define IN_F 128
#define OUT_F 64

#define BW_SHIFT 9
#define BWIDTH 512
#define NB 196              // ceil(100000/512)
#define CAP 20480           // per-bucket slot capacity; mean 16327, huge margin
#define CB 500              // bin blocks (NE = 500*6400 exactly)
#define EPB 6400            // edges per bin block
#define NQ (EPB / 4)        // 1600 int4 per block

// ---------------- phase 1: fused count + local sort + coalesced scatter ----------------
// LDS-staged counting sort per block; ~46 KB LDS -> 2 blocks/CU (32 waves/CU).
__global__ __launch_bounds__(1024) void bin_kernel(const int* __restrict__ src,
                                                   const int* __restrict__ dst,
                                                   int* __restrict__ curS_g,
                                                   int* __restrict__ curD_g,
                                                   unsigned short* __restrict__ srcloc,
                                                   int* __restrict__ pack,
                                                   const float* __restrict__ W,
                                                   const float* __restrict__ bias,
                                                   float* __restrict__ wbar,
                                                   float* __restrict__ bbar) {
    __shared__ int hs[NB], hd[NB];          // per-bucket counts
    __shared__ int lS[NB], lD[NB];          // local segment starts in staging
    __shared__ int cS[NB], cD[NB];          // scatter cursors
    __shared__ int gS[NB], gD[NB];          // reserved global bases
    __shared__ int scanbuf[256];
    __shared__ unsigned short stS[EPB];     // 12.8 KB staging (srcloc)
    __shared__ int stD[EPB];                // 25.6 KB staging (pack)
    const int blk = blockIdx.x;
    const int t = threadIdx.x;
    for (int k = t; k < NB; k += 1024) { hs[k] = 0; hd[k] = 0; }
    __syncthreads();

    const int4* s4 = (const int4*)(src + blk * EPB);
    const int4* d4 = (const int4*)(dst + blk * EPB);
    // cache chunk in registers (static indexing; iter1 active only for t < NQ-1024)
    int4 sc[2], dc[2];
    #pragma unroll
    for (int u = 0; u < 2; ++u) {
        int i = t + u * 1024;
        if (i < NQ) { sc[u] = s4[i]; dc[u] = d4[i]; }
        else        { sc[u] = make_int4(-1, -1, -1, -1); dc[u] = sc[u]; }
    }
    // pass 1: histogram
    #pragma unroll
    for (int u = 0; u < 2; ++u) {
        if (sc[u].x >= 0) {
            atomicAdd(&hs[sc[u].x >> BW_SHIFT], 1);
            atomicAdd(&hs[sc[u].y >> BW_SHIFT], 1);
            atomicAdd(&hs[sc[u].z >> BW_SHIFT], 1);
            atomicAdd(&hs[sc[u].w >> BW_SHIFT], 1);
            atomicAdd(&hd[dc[u].x >> BW_SHIFT], 1);
            atomicAdd(&hd[dc[u].y >> BW_SHIFT], 1);
            atomicAdd(&hd[dc[u].z >> BW_SHIFT], 1);
            atomicAdd(&hd[dc[u].w >> BW_SHIFT], 1);
        }
    }
    __syncthreads();
    // local exclusive prefix over buckets: S side
    if (t < 256) scanbuf[t] = (t < NB) ? hs[t] : 0;
    __syncthreads();
    #pragma unroll
    for (int off = 1; off < 256; off <<= 1) {
        int x = (t < 256 && t >= off) ? scanbuf[t - off] : 0;
        __syncthreads();
        if (t < 256) scanbuf[t] += x;
        __syncthreads();
    }
    if (t < NB) { int e = scanbuf[t] - hs[t]; lS[t] = e; cS[t] = e; }
    __syncthreads();
    // D side (reuse scanbuf)
    if (t < 256) scanbuf[t] = (t < NB) ? hd[t] : 0;
    __syncthreads();
    #pragma unroll
    for (int off = 1; off < 256; off <<= 1) {
        int x = (t < 256 && t >= off) ? scanbuf[t - off] : 0;
        __syncthreads();
        if (t < 256) scanbuf[t] += x;
        __syncthreads();
    }
    if (t < NB) { int e = scanbuf[t] - hd[t]; lD[t] = e; cD[t] = e; }
    // reserve global segments (one atomic per (block,bucket))
    if (t < NB) {
        gS[t] = t * CAP + atomicAdd(&curS_g[t], hs[t]);
        gD[t] = t * CAP + atomicAdd(&curD_g[t], hd[t]);
    }
    __syncthreads();
    // pass 2: scatter into LDS staging (sorted by bucket)
    #pragma unroll
    for (int u = 0; u < 2; ++u) {
        if (sc[u].x >= 0) {
            int p;
            p = atomicAdd(&cS[sc[u].x >> BW_SHIFT], 1); stS[p] = (unsigned short)(sc[u].x & (BWIDTH - 1));
            p = atomicAdd(&cS[sc[u].y >> BW_SHIFT], 1); stS[p] = (unsigned short)(sc[u].y & (BWIDTH - 1));
            p = atomicAdd(&cS[sc[u].z >> BW_SHIFT], 1); stS[p] = (unsigned short)(sc[u].z & (BWIDTH - 1));
            p = atomicAdd(&cS[sc[u].w >> BW_SHIFT], 1); stS[p] = (unsigned short)(sc[u].w & (BWIDTH - 1));
            // pack: src node id (17 bits) | dst local id (9 bits) << 17
            p = atomicAdd(&cD[dc[u].x >> BW_SHIFT], 1); stD[p] = sc[u].x | ((dc[u].x & (BWIDTH - 1)) << 17);
            p = atomicAdd(&cD[dc[u].y >> BW_SHIFT], 1); stD[p] = sc[u].y | ((dc[u].y & (BWIDTH - 1)) << 17);
            p = atomicAdd(&cD[dc[u].z >> BW_SHIFT], 1); stD[p] = sc[u].z | ((dc[u].z & (BWIDTH - 1)) << 17);
            p = atomicAdd(&cD[dc[u].w >> BW_SHIFT], 1); stD[p] = sc[u].w | ((dc[u].w & (BWIDTH - 1)) << 17);
        }
    }
    __syncthreads();
    // pass 3: coalesced copy-out, 16-lane group per bucket (segments avg ~33 elems)
    const int grp = t >> 4, gl = t & 15;    // 64 groups
    for (int k = grp; k < NB; k += 64) {
        int len = hs[k], lb = lS[k], gb = gS[k];
        for (int j = gl; j < len; j += 16) srcloc[gb + j] = stS[lb + j];
        len = hd[k]; lb = lD[k]; gb = gD[k];
        for (int j = gl; j < len; j += 16) pack[gb + j] = stD[lb + j];
    }
    // fold wbar/bbar into block 0
    if (blk == 0) {
        if (t < IN_F) {
            float s = 0.f;
            for (int j = 0; j < OUT_F; ++j) s += W[t * OUT_F + j];
            wbar[t] = s * (1.0f / OUT_F);
        } else if (t == IN_F) {
            float sb = 0.f;
            for (int j = 0; j < OUT_F; ++j) sb += bias[j];
            *bbar = sb * (1.0f / OUT_F);
        }
    }
}

// ---------------- phase 2: fused degnorm + node dot per src-bucket ----------------
__global__ __launch_bounds__(1024) void bucket_scalar_kernel(const unsigned short* __restrict__ srcloc,
                                                             const int* __restrict__ curS_g,
                                                             const float* __restrict__ features,
                                                             const float* __restrict__ wbar,
                                                             float* __restrict__ sval) {
    __shared__ int cnt[BWIDTH];
    __shared__ float4 wsh[IN_F / 4];
    const int k = blockIdx.x;
    const int t = threadIdx.x;
    if (t < IN_F / 4) wsh[t] = ((const float4*)wbar)[t];
    for (int i = t; i < BWIDTH; i += 1024) cnt[i] = 0;
    __syncthreads();
    const int base = k * CAP;
    const int len = curS_g[k];
    for (int i = t; i < len; i += 1024) atomicAdd(&cnt[srcloc[base + i]], 1);
    __syncthreads();
    // 16-lane groups, 4 nodes per wave in flight, 8 iterations
    const int wv = t >> 6, ln = t & 63;
    const int sub = ln >> 4, sl = ln & 15;
    const float4 wa = wsh[sl], wb = wsh[sl + 16];
    #pragma unroll
    for (int it = 0; it < 8; ++it) {
        const int loc = (wv << 5) + (it << 2) + sub;
        const int node = (k << BW_SHIFT) + loc;
        if (node < NN) {
            const float4* f4 = (const float4*)(features + (size_t)node * IN_F);
            float4 fa = f4[sl], fb = f4[sl + 16];
            float p = fa.x * wa.x + fa.y * wa.y + fa.z * wa.z + fa.w * wa.w
                    + fb.x * wb.x + fb.y * wb.y + fb.z * wb.z + fb.w * wb.w;
            #pragma unroll
            for (int off = 1; off < 16; off <<= 1) p += __shfl_xor(p, off);
            if (sl == 0) sval[node] = p * rsqrtf(fmaxf((float)cnt[loc], 1.0f));
        }
    }
}

// ---------------- phase 3: per-dst-bucket accumulate + finalize ----------------
__global__ __launch_bounds__(1024) void accum_kernel(const int* __restrict__ pack,
                                                     const int* __restrict__ curD_g,
                                                     const float* __restrict__ sval,
                                                     const float* __restrict__ bbar,
                                                     float* __restrict__ out) {
    __shared__ float agg[BWIDTH];
    __shared__ int cnt[BWIDTH];
    const int k = blockIdx.x;
    const int t = threadIdx.x;
    for (int i = t; i < BWIDTH; i += 1024) { agg[i] = 0.f; cnt[i] = 0; }
    __syncthreads();
    const int base = k * CAP;
    const int len = curD_g[k];
    for (int i = t; i < len; i += 1024) {
        int p = pack[base + i];
        int s = p & 0x1FFFF;
        int loc = (p >> 17) & (BWIDTH - 1);
        float v = sval[s];
        atomicAdd(&agg[loc], v);
        atomicAdd(&cnt[loc], 1);
    }
    __syncthreads();
    for (int i = t; i < BWIDTH; i += 1024) {
        int node = (k << BW_SHIFT) + i;
        if (node < NN) out[node] = agg[i] * rsqrtf(fmaxf((float)cnt[i], 1.0f)) + bbar[0];
    }
}

// ================= fallback (R1 atomic path, needs only ~1.6 MB ws) =================
__global__ void wbar_fb_kernel(const float* __restrict__ W, const float* __restrict__ bias,
                               float* __restrict__ wbar, float* __restrict__ bbar) {
    int k = threadIdx.x;
    float s = 0.f;
    for (int j = 0; j < OUT_F; ++j) s += W[k * OUT_F + j];
    wbar[k] = s * (1.0f / OUT_F);
    if (k == 0) {
        float sb = 0.f;
        for (int j = 0; j < OUT_F; ++j) sb += bias[j];
        *bbar = sb * (1.0f / OUT_F);
    }
}
__global__ void deg_kernel(const int* __restrict__ src, const int* __restrict__ dst,
                           int* __restrict__ deg_out, int* __restrict__ deg_in) {
    const int nq = NE / 4;
    int i = blockIdx.x * blockDim.x + threadIdx.x;
    const int stride = gridDim.x * blockDim.x;
    const int4* src4 = (const int4*)src;
    const int4* dst4 = (const int4*)dst;
    for (; i < nq; i += stride) {
        int4 s = src4[i];
        int4 d = dst4[i];
        atomicAdd(&deg_out[s.x], 1); atomicAdd(&deg_out[s.y], 1);
        atomicAdd(&deg_out[s.z], 1); atomicAdd(&deg_out[s.w], 1);
        atomicAdd(&deg_in[d.x], 1);  atomicAdd(&deg_in[d.y], 1);
        atomicAdd(&deg_in[d.z], 1);  atomicAdd(&deg_in[d.w], 1);
    }
}
__global__ void node_scalar_deg_kernel(const float* __restrict__ features,
                                       const int* __restrict__ deg_out,
                                       const float* __restrict__ wbar,
                                       float* __restrict__ sval) {
    const int lane = threadIdx.x & 63;
    const int wave = threadIdx.x >> 6;
    const int node = blockIdx.x * 4 + wave;
    if (node >= NN) return;
    const float2* f2 = (const float2*)(features + (size_t)node * IN_F);
    const float2* w2 = (const float2*)wbar;
    float2 f = f2[lane];
    float2 w = w2[lane];
    float p = f.x * w.x + f.y * w.y;
    #pragma unroll
    for (int off = 32; off > 0; off >>= 1) p += __shfl_down(p, off);
    if (lane == 0) {
        float d = (float)deg_out[node];
        sval[node] = p * rsqrtf(fmaxf(d, 1.0f));
    }
}
__global__ void scatter_kernel(const int* __restrict__ src, const int* __restrict__ dst,
                               const float* __restrict__ sval, float* __restrict__ agg) {
    const int nq = NE / 4;
    int i = blockIdx.x * blockDim.x + threadIdx.x;
    const int stride = gridDim.x * blockDim.x;
    const int4* src4 = (const int4*)src;
    const int4* dst4 = (const int4*)dst;
    for (; i < nq; i += stride) {
        int4 s = src4[i];
        int4 d = dst4[i];
        atomicAdd(&agg[d.x], sval[s.x]);
        atomicAdd(&agg[d.y], sval[s.y]);
        atomicAdd(&agg[d.z], sval[s.z]);
        atomicAdd(&agg[d.w], sval[s.w]);
    }
}
__global__ void final_kernel(const float* __restrict__ agg, const int* __restrict__ deg_in,
                             const float* __restrict__ bbar, float* __restrict__ out) {
    int n = blockIdx.x * blockDim.x + threadIdx.x;
    if (n >= NN) return;
    float d = (float)deg_in[n];
    out[n] = agg[n] * rsqrtf(fmaxf(d, 1.0f)) + *bbar;
}

extern "C" void kernel_launch(void* const* d_in, const int* in_sizes, int n_in,
                              void* d_out, int out_size, void* d_ws, size_t ws_size,
                              hipStream_t stream) {
    const float* features = (const float*)d_in[0];
    const float* W        = (const float*)d_in[1];
    const float* bias     = (const float*)d_in[2];
    const int*   src      = (const int*)d_in[3];
    const int*   dst      = (const int*)d_in[4];
    float* out = (float*)d_out;

    // fast-path workspace layout (4-byte words):
    // [0, NB*CAP)            pack (int)
    // [+NB*CAP/2]            srcloc (ushort[NB*CAP])
    // [+NB]                  curS
    // [+NB]                  curD
    // [+NN]                  sval
    // [+IN_F]                wbar
    // [+1]                   bbar
    size_t need_words = (size_t)NB * CAP + (size_t)NB * CAP / 2 + 2 * NB
                      + (size_t)NN + IN_F + 1;
    if (ws_size >= need_words * 4 + 64) {
        int* w_ = (int*)d_ws;
        int*  pack              = w_;
        unsigned short* srcloc  = (unsigned short*)(w_ + (size_t)NB * CAP);
        int*  curS_g            = w_ + (size_t)NB * CAP + (size_t)NB * CAP / 2;
        int*  curD_g            = curS_g + NB;
        float* sval             = (float*)(curD_g + NB);
        float* wbar             = sval + NN;
        float* bbar             = wbar + IN_F;

        hipMemsetAsync(curS_g, 0, 2 * NB * sizeof(int), stream);
        bin_kernel<<<CB, 1024, 0, stream>>>(src, dst, curS_g, curD_g, srcloc, pack,
                                            W, bias, wbar, bbar);
        bucket_scalar_kernel<<<NB, 1024, 0, stream>>>(srcloc, curS_g, features, wbar, sval);
        accum_kernel<<<NB, 1024, 0, stream>>>(pack, curD_g, sval, bbar, out);
    } else {
        // fallback: R1 atomic path
        int*   deg_out = (int*)d_ws;
        int*   deg_in  = deg_out + NN;
        float* agg     = (float*)(deg_in + NN);
        float* sval    = agg + NN;
        float* wbar    = sval + NN;
        float* bbar    = wbar + IN_F;
        hipMemsetAsync(d_ws, 0, (size_t)3 * NN * sizeof(int), stream);
        wbar_fb_kernel<<<1, 128, 0, stream>>>(W, bias, wbar, bbar);
        deg_kernel<<<2048, 256, 0, stream>>>(src, dst, deg_out, deg_in);
        node_scalar_deg_kernel<<<(NN + 3) / 4, 256, 0, stream>>>(features, deg_out, wbar, sval);
        scatter_kernel<<<2048, 256, 0, stream>>>(src, dst, sval, agg);
        final_kernel<<<(NN + 255) / 256, 256, 0, stream>>>(agg, deg_in, bbar, out);
    }
}

// Round 10
// 157.078 us; speedup vs baseline: 3.3813x; 1.0078x over previous
//
#include <hip/hip_runtime.h>

#define NN 100000
#define NE 3200000
#define IN_F 128
#define OUT_F 64

#define BW_SHIFT 9
#define BWIDTH 512
#define NB 196              // ceil(100000/512)
#define CAP 20480           // per-bucket slot capacity; mean 16327, huge margin
#define CB 500              // bin blocks (NE = 500*6400 exactly)
#define EPB 6400            // edges per bin block
#define NQ (EPB / 4)        // 1600 int4 per block

// ---------------- phase 1: fused count + local sort + coalesced scatter ----------------
// LDS-staged counting sort; wave-shfl scans (3 barriers) + 2x replicated histograms.
__global__ __launch_bounds__(1024) void bin_kernel(const int* __restrict__ src,
                                                   const int* __restrict__ dst,
                                                   int* __restrict__ curS_g,
                                                   int* __restrict__ curD_g,
                                                   unsigned short* __restrict__ srcloc,
                                                   int* __restrict__ pack,
                                                   const float* __restrict__ W,
                                                   const float* __restrict__ bias,
                                                   float* __restrict__ wbar,
                                                   float* __restrict__ bbar) {
    __shared__ int hs[2][NB], hd[2][NB];    // replicated per-bucket counts
    __shared__ int lS[NB], lD[NB];          // local segment starts in staging
    __shared__ int cS[NB], cD[NB];          // scatter cursors
    __shared__ int gS[NB], gD[NB];          // reserved global bases
    __shared__ int wtot[8];                 // per-wave scan totals (4 S + 4 D)
    __shared__ unsigned short stS[EPB];     // 12.8 KB staging (srcloc)
    __shared__ int stD[EPB];                // 25.6 KB staging (pack)
    const int blk = blockIdx.x;
    const int t = threadIdx.x;
    for (int k = t; k < 2 * NB; k += 1024) { (&hs[0][0])[k] = 0; (&hd[0][0])[k] = 0; }
    __syncthreads();

    const int4* s4 = (const int4*)(src + blk * EPB);
    const int4* d4 = (const int4*)(dst + blk * EPB);
    // cache chunk in registers (static indexing)
    int4 sc[2], dc[2];
    #pragma unroll
    for (int u = 0; u < 2; ++u) {
        int i = t + u * 1024;
        if (i < NQ) { sc[u] = s4[i]; dc[u] = d4[i]; }
        else        { sc[u] = make_int4(-1, -1, -1, -1); dc[u] = sc[u]; }
    }
    // pass 1: replicated histogram (replica by thread half -> halved contention)
    const int r = (t >> 9) & 1;
    #pragma unroll
    for (int u = 0; u < 2; ++u) {
        if (sc[u].x >= 0) {
            atomicAdd(&hs[r][sc[u].x >> BW_SHIFT], 1);
            atomicAdd(&hs[r][sc[u].y >> BW_SHIFT], 1);
            atomicAdd(&hs[r][sc[u].z >> BW_SHIFT], 1);
            atomicAdd(&hs[r][sc[u].w >> BW_SHIFT], 1);
            atomicAdd(&hd[r][dc[u].x >> BW_SHIFT], 1);
            atomicAdd(&hd[r][dc[u].y >> BW_SHIFT], 1);
            atomicAdd(&hd[r][dc[u].z >> BW_SHIFT], 1);
            atomicAdd(&hd[r][dc[u].w >> BW_SHIFT], 1);
        }
    }
    __syncthreads();
    // wave-shfl exclusive scans: threads 0-255 do S, 256-511 do D, concurrently
    const int side = (t < 256) ? 0 : ((t < 512) ? 1 : -1);
    const int idx = t & 255;
    const int ln6 = t & 63;
    int orig = 0;
    if (side == 0 && idx < NB) orig = hs[0][idx] + hs[1][idx];
    if (side == 1 && idx < NB) orig = hd[0][idx] + hd[1][idx];
    int val = orig;
    if (side >= 0) {
        #pragma unroll
        for (int off = 1; off < 64; off <<= 1) {
            int x = __shfl_up(val, off);
            if (ln6 >= off) val += x;
        }
        if (ln6 == 63) wtot[t >> 6] = val;   // waves 0-3 = S, 4-7 = D
    }
    __syncthreads();
    if (side >= 0) {
        int base = 0;
        const int w0 = side * 4, myw = t >> 6;
        for (int w = w0; w < myw; ++w) base += wtot[w];
        const int excl = val + base - orig;
        if (idx < NB) {
            if (side == 0) {
                lS[idx] = excl; cS[idx] = excl; hs[0][idx] = orig;
                gS[idx] = idx * CAP + atomicAdd(&curS_g[idx], orig);
            } else {
                lD[idx] = excl; cD[idx] = excl; hd[0][idx] = orig;
                gD[idx] = idx * CAP + atomicAdd(&curD_g[idx], orig);
            }
        }
    }
    __syncthreads();
    // pass 2: scatter into LDS staging (sorted by bucket)
    #pragma unroll
    for (int u = 0; u < 2; ++u) {
        if (sc[u].x >= 0) {
            int p;
            p = atomicAdd(&cS[sc[u].x >> BW_SHIFT], 1); stS[p] = (unsigned short)(sc[u].x & (BWIDTH - 1));
            p = atomicAdd(&cS[sc[u].y >> BW_SHIFT], 1); stS[p] = (unsigned short)(sc[u].y & (BWIDTH - 1));
            p = atomicAdd(&cS[sc[u].z >> BW_SHIFT], 1); stS[p] = (unsigned short)(sc[u].z & (BWIDTH - 1));
            p = atomicAdd(&cS[sc[u].w >> BW_SHIFT], 1); stS[p] = (unsigned short)(sc[u].w & (BWIDTH - 1));
            // pack: src node id (17 bits) | dst local id (9 bits) << 17
            p = atomicAdd(&cD[dc[u].x >> BW_SHIFT], 1); stD[p] = sc[u].x | ((dc[u].x & (BWIDTH - 1)) << 17);
            p = atomicAdd(&cD[dc[u].y >> BW_SHIFT], 1); stD[p] = sc[u].y | ((dc[u].y & (BWIDTH - 1)) << 17);
            p = atomicAdd(&cD[dc[u].z >> BW_SHIFT], 1); stD[p] = sc[u].z | ((dc[u].z & (BWIDTH - 1)) << 17);
            p = atomicAdd(&cD[dc[u].w >> BW_SHIFT], 1); stD[p] = sc[u].w | ((dc[u].w & (BWIDTH - 1)) << 17);
        }
    }
    __syncthreads();
    // pass 3: coalesced copy-out, 16-lane group per bucket (segments avg ~33 elems)
    const int grp = t >> 4, gl = t & 15;    // 64 groups
    for (int k = grp; k < NB; k += 64) {
        int len = hs[0][k], lb = lS[k], gb = gS[k];
        for (int j = gl; j < len; j += 16) srcloc[gb + j] = stS[lb + j];
        len = hd[0][k]; lb = lD[k]; gb = gD[k];
        for (int j = gl; j < len; j += 16) pack[gb + j] = stD[lb + j];
    }
    // fold wbar/bbar into block 0
    if (blk == 0) {
        if (t < IN_F) {
            float s = 0.f;
            for (int j = 0; j < OUT_F; ++j) s += W[t * OUT_F + j];
            wbar[t] = s * (1.0f / OUT_F);
        } else if (t == IN_F) {
            float sb = 0.f;
            for (int j = 0; j < OUT_F; ++j) sb += bias[j];
            *bbar = sb * (1.0f / OUT_F);
        }
    }
}

// ---------------- phase 2: fused degnorm + node dot; 2 blocks per bucket ----------------
__global__ __launch_bounds__(1024) void bucket_scalar_kernel(const unsigned short* __restrict__ srcloc,
                                                             const int* __restrict__ curS_g,
                                                             const float* __restrict__ features,
                                                             const float* __restrict__ wbar,
                                                             float* __restrict__ sval) {
    __shared__ int cnt[256];
    __shared__ float4 wsh[IN_F / 4];
    const int k = blockIdx.x >> 1;
    const int half = blockIdx.x & 1;
    const int t = threadIdx.x;
    if (t < IN_F / 4) wsh[t] = ((const float4*)wbar)[t];
    if (t < 256) cnt[t] = 0;
    __syncthreads();
    const int base = k * CAP;
    const int len = curS_g[k];
    const int hsel = half << 8;
    for (int i = t; i < len; i += 1024) {
        int l = srcloc[base + i];
        if ((l & 256) == hsel) atomicAdd(&cnt[l & 255], 1);
    }
    __syncthreads();
    // dot for this half's 256 nodes: 16-lane groups, 4 iterations
    const int wv = t >> 6, ln = t & 63;
    const int sub = ln >> 4, sl = ln & 15;
    const float4 wa = wsh[sl], wb = wsh[sl + 16];
    #pragma unroll
    for (int it = 0; it < 4; ++it) {
        const int loc256 = (wv << 4) + (it << 2) + sub;
        const int node = (k << BW_SHIFT) + (half << 8) + loc256;
        if (node < NN) {
            const float4* f4 = (const float4*)(features + (size_t)node * IN_F);
            float4 fa = f4[sl], fb = f4[sl + 16];
            float p = fa.x * wa.x + fa.y * wa.y + fa.z * wa.z + fa.w * wa.w
                    + fb.x * wb.x + fb.y * wb.y + fb.z * wb.z + fb.w * wb.w;
            #pragma unroll
            for (int off = 1; off < 16; off <<= 1) p += __shfl_xor(p, off);
            if (sl == 0) sval[node] = p * rsqrtf(fmaxf((float)cnt[loc256], 1.0f));
        }
    }
}

// ---------------- phase 3: per-dst-bucket accumulate + finalize ----------------
__global__ __launch_bounds__(1024) void accum_kernel(const int* __restrict__ pack,
                                                     const int* __restrict__ curD_g,
                                                     const float* __restrict__ sval,
                                                     const float* __restrict__ bbar,
                                                     float* __restrict__ out) {
    __shared__ float agg[BWIDTH];
    __shared__ int cnt[BWIDTH];
    const int k = blockIdx.x;
    const int t = threadIdx.x;
    for (int i = t; i < BWIDTH; i += 1024) { agg[i] = 0.f; cnt[i] = 0; }
    __syncthreads();
    const int base = k * CAP;
    const int len = curD_g[k];
    for (int i = t; i < len; i += 1024) {
        int p = pack[base + i];
        int s = p & 0x1FFFF;
        int loc = (p >> 17) & (BWIDTH - 1);
        float v = sval[s];
        atomicAdd(&agg[loc], v);
        atomicAdd(&cnt[loc], 1);
    }
    __syncthreads();
    for (int i = t; i < BWIDTH; i += 1024) {
        int node = (k << BW_SHIFT) + i;
        if (node < NN) out[node] = agg[i] * rsqrtf(fmaxf((float)cnt[i], 1.0f)) + bbar[0];
    }
}

// ================= fallback (R1 atomic path, needs only ~1.6 MB ws) =================
__global__ void wbar_fb_kernel(const float* __restrict__ W, const float* __restrict__ bias,
                               float* __restrict__ wbar, float* __restrict__ bbar) {
    int k = threadIdx.x;
    float s = 0.f;
    for (int j = 0; j < OUT_F; ++j) s += W[k * OUT_F + j];
    wbar[k] = s * (1.0f / OUT_F);
    if (k == 0) {
        float sb = 0.f;
        for (int j = 0; j < OUT_F; ++j) sb += bias[j];
        *bbar = sb * (1.0f / OUT_F);
    }
}
__global__ void deg_kernel(const int* __restrict__ src, const int* __restrict__ dst,
                           int* __restrict__ deg_out, int* __restrict__ deg_in) {
    const int nq = NE / 4;
    int i = blockIdx.x * blockDim.x + threadIdx.x;
    const int stride = gridDim.x * blockDim.x;
    const int4* src4 = (const int4*)src;
    const int4* dst4 = (const int4*)dst;
    for (; i < nq; i += stride) {
        int4 s = src4[i];
        int4 d = dst4[i];
        atomicAdd(&deg_out[s.x], 1); atomicAdd(&deg_out[s.y], 1);
        atomicAdd(&deg_out[s.z], 1); atomicAdd(&deg_out[s.w], 1);
        atomicAdd(&deg_in[d.x], 1);  atomicAdd(&deg_in[d.y], 1);
        atomicAdd(&deg_in[d.z], 1);  atomicAdd(&deg_in[d.w], 1);
    }
}
__global__ void node_scalar_deg_kernel(const float* __restrict__ features,
                                       const int* __restrict__ deg_out,
                                       const float* __restrict__ wbar,
                                       float* __restrict__ sval) {
    const int lane = threadIdx.x & 63;
    const int wave = threadIdx.x >> 6;
    const int node = blockIdx.x * 4 + wave;
    if (node >= NN) return;
    const float2* f2 = (const float2*)(features + (size_t)node * IN_F);
    const float2* w2 = (const float2*)wbar;
    float2 f = f2[lane];
    float2 w = w2[lane];
    float p = f.x * w.x + f.y * w.y;
    #pragma unroll
    for (int off = 32; off > 0; off >>= 1) p += __shfl_down(p, off);
    if (lane == 0) {
        float d = (float)deg_out[node];
        sval[node] = p * rsqrtf(fmaxf(d, 1.0f));
    }
}
__global__ void scatter_kernel(const int* __restrict__ src, const int* __restrict__ dst,
                               const float* __restrict__ sval, float* __restrict__ agg) {
    const int nq = NE / 4;
    int i = blockIdx.x * blockDim.x + threadIdx.x;
    const int stride = gridDim.x * blockDim.x;
    const int4* src4 = (const int4*)src;
    const int4* dst4 = (const int4*)dst;
    for (; i < nq; i += stride) {
        int4 s = src4[i];
        int4 d = dst4[i];
        atomicAdd(&agg[d.x], sval[s.x]);
        atomicAdd(&agg[d.y], sval[s.y]);
        atomicAdd(&agg[d.z], sval[s.z]);
        atomicAdd(&agg[d.w], sval[s.w]);
    }
}
__global__ void final_kernel(const float* __restrict__ agg, const int* __restrict__ deg_in,
                             const float* __restrict__ bbar, float* __restrict__ out) {
    int n = blockIdx.x * blockDim.x + threadIdx.x;
    if (n >= NN) return;
    float d = (float)deg_in[n];
    out[n] = agg[n] * rsqrtf(fmaxf(d, 1.0f)) + *bbar;
}

extern "C" void kernel_launch(void* const* d_in, const int* in_sizes, int n_in,
                              void* d_out, int out_size, void* d_ws, size_t ws_size,
                              hipStream_t stream) {
    const float* features = (const float*)d_in[0];
    const float* W        = (const float*)d_in[1];
    const float* bias     = (const float*)d_in[2];
    const int*   src      = (const int*)d_in[3];
    const int*   dst      = (const int*)d_in[4];
    float* out = (float*)d_out;

    // fast-path workspace layout (4-byte words):
    // [0, NB*CAP)            pack (int)
    // [+NB*CAP/2]            srcloc (ushort[NB*CAP])
    // [+NB]                  curS
    // [+NB]                  curD
    // [+NN]                  sval
    // [+IN_F]                wbar
    // [+1]                   bbar
    size_t need_words = (size_t)NB * CAP + (size_t)NB * CAP / 2 + 2 * NB
                      + (size_t)NN + IN_F + 1;
    if (ws_size >= need_words * 4 + 64) {
        int* w_ = (int*)d_ws;
        int*  pack              = w_;
        unsigned short* srcloc  = (unsigned short*)(w_ + (size_t)NB * CAP);
        int*  curS_g            = w_ + (size_t)NB * CAP + (size_t)NB * CAP / 2;
        int*  curD_g            = curS_g + NB;
        float* sval             = (float*)(curD_g + NB);
        float* wbar             = sval + NN;
        float* bbar             = wbar + IN_F;

        hipMemsetAsync(curS_g, 0, 2 * NB * sizeof(int), stream);
        bin_kernel<<<CB, 1024, 0, stream>>>(src, dst, curS_g, curD_g, srcloc, pack,
                                            W, bias, wbar, bbar);
        bucket_scalar_kernel<<<2 * NB, 1024, 0, stream>>>(srcloc, curS_g, features, wbar, sval);
        accum_kernel<<<NB, 1024, 0, stream>>>(pack, curD_g, sval, bbar, out);
    } else {
        // fallback: R1 atomic path
        int*   deg_out = (int*)d_ws;
        int*   deg_in  = deg_out + NN;
        float* agg     = (float*)(deg_in + NN);
        float* sval    = agg + NN;
        float* wbar    = sval + NN;
        float* bbar    = wbar + IN_F;
        hipMemsetAsync(d_ws, 0, (size_t)3 * NN * sizeof(int), stream);
        wbar_fb_kernel<<<1, 128, 0, stream>>>(W, bias, wbar, bbar);
        deg_kernel<<<2048, 256, 0, stream>>>(src, dst, deg_out, deg_in);
        node_scalar_deg_kernel<<<(NN + 3) / 4, 256, 0, stream>>>(features, deg_out, wbar, sval);
        scatter_kernel<<<2048, 256, 0, stream>>>(src, dst, sval, agg);
        final_kernel<<<(NN + 255) / 256, 256, 0, stream>>>(agg, deg_in, bbar, out);
    }
}